// Round 1
// baseline (1328.848 us; speedup 1.0000x reference)
//
#include <hip/hip_runtime.h>
#include <math.h>

#define BN 8192      // B*N tokens
#define DIM 1024     // D
#define NE 8         // E experts
#define RR 256       // R
#define TT 32        // token tile per expert block

// ---------------- ws layout (ints) ----------------
// [0..8)    counts
// [8..16)   offsets
// [16..24)  fill
// [32..32+16384)          topi   (token*2+k -> expert idx)
// [+16384 .. +32768)      topw   (float)
// [+32768 .. +49152)      btok   (grouped token ids)
// [+49152 .. +65536)      bw     (grouped gate weights, float)

__global__ __launch_bounds__(256) void k_router(const float* __restrict__ x,
                                                const float* __restrict__ gw,
                                                int* __restrict__ counts,
                                                int* __restrict__ topi,
                                                float* __restrict__ topw) {
    int wid  = (blockIdx.x * blockDim.x + threadIdx.x) >> 6;  // one wave per token
    int lane = threadIdx.x & 63;
    if (wid >= BN) return;
    const float* xp = x + (size_t)wid * DIM;
    float lg[NE];
#pragma unroll
    for (int e = 0; e < NE; ++e) lg[e] = 0.f;
    for (int d = lane; d < DIM; d += 64) {
        float xv = xp[d];
        const float* g = gw + d * NE;
#pragma unroll
        for (int e = 0; e < NE; ++e) lg[e] += xv * g[e];
    }
#pragma unroll
    for (int off = 32; off; off >>= 1) {
#pragma unroll
        for (int e = 0; e < NE; ++e) lg[e] += __shfl_xor(lg[e], off, 64);
    }
    if (lane == 0) {
        // top-2 (stable: strict > keeps lowest index on ties, matches lax.top_k)
        float best = lg[0]; int bi = 0;
#pragma unroll
        for (int e = 1; e < NE; ++e) if (lg[e] > best) { best = lg[e]; bi = e; }
        float sec = -3.4e38f; int si = 0;
#pragma unroll
        for (int e = 0; e < NE; ++e) if (e != bi && lg[e] > sec) { sec = lg[e]; si = e; }
        float p  = __expf(sec - best);
        float w0 = 1.f / (1.f + p);
        float w1 = p * w0;
        topi[wid * 2 + 0] = bi;  topw[wid * 2 + 0] = w0;
        topi[wid * 2 + 1] = si;  topw[wid * 2 + 1] = w1;
        atomicAdd(&counts[bi], 1);
        atomicAdd(&counts[si], 1);
    }
}

__global__ void k_scan(const int* __restrict__ counts, int* __restrict__ offsets,
                       int* __restrict__ fill) {
    if (threadIdx.x == 0) {
        int acc = 0;
        for (int e = 0; e < NE; ++e) { offsets[e] = acc; acc += counts[e]; }
    }
    if (threadIdx.x < NE) fill[threadIdx.x] = 0;
}

__global__ __launch_bounds__(256) void k_fill(const int* __restrict__ topi,
                                              const float* __restrict__ topw,
                                              const int* __restrict__ offsets,
                                              int* __restrict__ fill,
                                              int* __restrict__ btok,
                                              float* __restrict__ bw) {
    int i = blockIdx.x * 256 + threadIdx.x;
    if (i >= BN * 2) return;
    int e = topi[i];
    int pos = atomicAdd(&fill[e], 1);
    int slot = offsets[e] + pos;
    btok[slot] = i >> 1;
    bw[slot]   = topw[i];
}

__global__ __launch_bounds__(256) void k_expert(const float* __restrict__ x,
                                                const float* __restrict__ Wu,
                                                const float* __restrict__ Wv,
                                                const float* __restrict__ Wo,
                                                const int* __restrict__ counts,
                                                const int* __restrict__ offsets,
                                                const int* __restrict__ btok,
                                                const float* __restrict__ bw,
                                                float* __restrict__ out) {
    int e  = blockIdx.y;
    int ne = counts[e];
    int t0 = blockIdx.x * TT;
    if (t0 >= ne) return;
    int nt = min(TT, ne - t0);
    int start = offsets[e] + t0;
    int j = threadIdx.x;   // = r column for up phase, = d-lane for down phase

    __shared__ float xs[TT][64];    // 8 KB x stage
    __shared__ float sls[TT][RR];   // 32 KB silu(u)*v*w
    __shared__ int   tokL[TT];
    __shared__ float gwL[TT];

    if (j < TT) {
        if (j < nt) { tokL[j] = btok[start + j]; gwL[j] = bw[start + j]; }
        else        { tokL[j] = 0;               gwL[j] = 0.f; }
    }
    __syncthreads();

    float au[TT], av[TT];
#pragma unroll
    for (int t = 0; t < TT; ++t) { au[t] = 0.f; av[t] = 0.f; }

    const float* WuE = Wu + (size_t)e * DIM * RR;
    const float* WvE = Wv + (size_t)e * DIM * RR;

    for (int d0 = 0; d0 < DIM; d0 += 64) {
        __syncthreads();  // xs reuse guard
        for (int idx = j; idx < TT * 64; idx += 256) {
            int t = idx >> 6, dd = idx & 63;
            xs[t][dd] = (t < nt) ? x[(size_t)tokL[t] * DIM + d0 + dd] : 0.f;
        }
        __syncthreads();
        for (int dd = 0; dd < 64; dd += 4) {
            float wu0 = WuE[(size_t)(d0 + dd + 0) * RR + j];
            float wu1 = WuE[(size_t)(d0 + dd + 1) * RR + j];
            float wu2 = WuE[(size_t)(d0 + dd + 2) * RR + j];
            float wu3 = WuE[(size_t)(d0 + dd + 3) * RR + j];
            float wv0 = WvE[(size_t)(d0 + dd + 0) * RR + j];
            float wv1 = WvE[(size_t)(d0 + dd + 1) * RR + j];
            float wv2 = WvE[(size_t)(d0 + dd + 2) * RR + j];
            float wv3 = WvE[(size_t)(d0 + dd + 3) * RR + j];
#pragma unroll
            for (int t = 0; t < TT; ++t) {
                float4 xv = *(const float4*)&xs[t][dd];
                au[t] += xv.x * wu0; au[t] += xv.y * wu1;
                au[t] += xv.z * wu2; au[t] += xv.w * wu3;
                av[t] += xv.x * wv0; av[t] += xv.y * wv1;
                av[t] += xv.z * wv2; av[t] += xv.w * wv3;
            }
        }
    }
    __syncthreads();
#pragma unroll
    for (int t = 0; t < TT; ++t) {
        float u = au[t], v = av[t];
        float s = (u / (1.f + __expf(-u))) * v * gwL[t];
        sls[t][j] = s;
    }
    __syncthreads();

    const float* WoE = Wo + (size_t)e * RR * DIM;
    for (int c = 0; c < 4; ++c) {
        int d = c * 256 + j;
        float y[TT];
#pragma unroll
        for (int t = 0; t < TT; ++t) y[t] = 0.f;
        for (int r = 0; r < RR; r += 4) {
            float wo0 = WoE[(size_t)(r + 0) * DIM + d];
            float wo1 = WoE[(size_t)(r + 1) * DIM + d];
            float wo2 = WoE[(size_t)(r + 2) * DIM + d];
            float wo3 = WoE[(size_t)(r + 3) * DIM + d];
#pragma unroll
            for (int t = 0; t < TT; ++t) {
                float4 sv = *(const float4*)&sls[t][r];
                y[t] += sv.x * wo0; y[t] += sv.y * wo1;
                y[t] += sv.z * wo2; y[t] += sv.w * wo3;
            }
        }
        for (int t = 0; t < nt; ++t) {
            atomicAdd(&out[(size_t)tokL[t] * DIM + d], y[t]);
        }
    }
}

extern "C" void kernel_launch(void* const* d_in, const int* in_sizes, int n_in,
                              void* d_out, int out_size, void* d_ws, size_t ws_size,
                              hipStream_t stream) {
    const float* x  = (const float*)d_in[0];
    const float* gw = (const float*)d_in[1];
    const float* Wu = (const float*)d_in[2];
    const float* Wv = (const float*)d_in[3];
    const float* Wo = (const float*)d_in[4];
    float* out = (float*)d_out;

    int*   wsi     = (int*)d_ws;
    int*   counts  = wsi + 0;
    int*   offsets = wsi + 8;
    int*   fill    = wsi + 16;
    int*   topi    = wsi + 32;
    float* topw    = (float*)(wsi + 32 + 16384);
    int*   btok    = wsi + 32 + 32768;
    float* bw      = (float*)(wsi + 32 + 49152);

    hipMemsetAsync(d_ws, 0, 128, stream);
    hipMemsetAsync(d_out, 0, (size_t)BN * DIM * sizeof(float), stream);

    k_router<<<dim3(BN / 4), 256, 0, stream>>>(x, gw, counts, topi, topw);
    k_scan<<<1, 64, 0, stream>>>(counts, offsets, fill);
    k_fill<<<dim3(BN * 2 / 256), 256, 0, stream>>>(topi, topw, offsets, fill, btok, bw);
    k_expert<<<dim3(BN / TT, NE), 256, 0, stream>>>(x, Wu, Wv, Wo, counts, offsets,
                                                    btok, bw, out);
}

// Round 3
// 565.307 us; speedup vs baseline: 2.3507x; 2.3507x over previous
//
#include <hip/hip_runtime.h>
#include <math.h>

#define BN 8192      // B*N tokens
#define DIM 1024     // D
#define NE 8         // E experts
#define RR 256       // R

using bf16x8 = __attribute__((ext_vector_type(8))) short;
using f32x4  = __attribute__((ext_vector_type(4))) float;

__device__ inline unsigned short f2bf(float f) {
    unsigned int u = __float_as_uint(f);
    u = (u + 0x7fffu + ((u >> 16) & 1u)) >> 16;
    return (unsigned short)u;
}

// ---------------- routing ----------------
__global__ __launch_bounds__(256) void k_router(const float* __restrict__ x,
                                                const float* __restrict__ gw,
                                                int* __restrict__ counts,
                                                int* __restrict__ topi,
                                                float* __restrict__ topw) {
    int wid  = (blockIdx.x * blockDim.x + threadIdx.x) >> 6;  // one wave per token
    int lane = threadIdx.x & 63;
    if (wid >= BN) return;
    const float* xp = x + (size_t)wid * DIM;
    float lg[NE];
#pragma unroll
    for (int e = 0; e < NE; ++e) lg[e] = 0.f;
    for (int d = lane; d < DIM; d += 64) {
        float xv = xp[d];
        const float* g = gw + d * NE;
#pragma unroll
        for (int e = 0; e < NE; ++e) lg[e] += xv * g[e];
    }
#pragma unroll
    for (int off = 32; off; off >>= 1) {
#pragma unroll
        for (int e = 0; e < NE; ++e) lg[e] += __shfl_xor(lg[e], off, 64);
    }
    if (lane == 0) {
        float best = lg[0]; int bi = 0;
#pragma unroll
        for (int e = 1; e < NE; ++e) if (lg[e] > best) { best = lg[e]; bi = e; }
        float sec = -3.4e38f; int si = 0;
#pragma unroll
        for (int e = 0; e < NE; ++e) if (e != bi && lg[e] > sec) { sec = lg[e]; si = e; }
        float p  = __expf(sec - best);
        float w0 = 1.f / (1.f + p);
        float w1 = p * w0;
        topi[wid * 2 + 0] = bi;  topw[wid * 2 + 0] = w0;
        topi[wid * 2 + 1] = si;  topw[wid * 2 + 1] = w1;
        atomicAdd(&counts[bi], 1);
        atomicAdd(&counts[si], 1);
    }
}

__global__ void k_scan(const int* __restrict__ counts, int* __restrict__ offsets,
                       int* __restrict__ fill) {
    if (threadIdx.x == 0) {
        int acc = 0;
        for (int e = 0; e < NE; ++e) { offsets[e] = acc; acc += counts[e]; }
    }
    if (threadIdx.x < NE) fill[threadIdx.x] = 0;
}

__global__ __launch_bounds__(256) void k_fill(const int* __restrict__ topi,
                                              const float* __restrict__ topw,
                                              const int* __restrict__ offsets,
                                              int* __restrict__ fill,
                                              int* __restrict__ btok,
                                              float* __restrict__ bw) {
    int i = blockIdx.x * 256 + threadIdx.x;
    if (i >= BN * 2) return;
    int e = topi[i];
    int pos = atomicAdd(&fill[e], 1);
    int slot = offsets[e] + pos;
    btok[slot] = i >> 1;
    bw[slot]   = topw[i];
}

// ---------------- prep: fp32 -> bf16 conversions ----------------
__global__ __launch_bounds__(256) void k_cvt_x(const float* __restrict__ x,
                                               unsigned short* __restrict__ xb) {
    int idx = blockIdx.x * 256 + threadIdx.x;           // handles 8 elements
    const float4* xf = (const float4*)x;
    float4 a = xf[idx * 2 + 0];
    float4 b = xf[idx * 2 + 1];
    ushort4 lo = { f2bf(a.x), f2bf(a.y), f2bf(a.z), f2bf(a.w) };
    ushort4 hi = { f2bf(b.x), f2bf(b.y), f2bf(b.z), f2bf(b.w) };
    ushort4* o = (ushort4*)(xb + (size_t)idx * 8);
    o[0] = lo; o[1] = hi;
}

// transpose+convert: in [E][M][N] fp32 -> out [E][N][M] bf16
__global__ __launch_bounds__(256) void k_cvt_w(const float* __restrict__ in,
                                               unsigned short* __restrict__ out,
                                               int M, int N) {
    int e  = blockIdx.z;
    int n0 = blockIdx.x * 32, m0 = blockIdx.y * 32;
    __shared__ float t[32][33];
    int tx = threadIdx.x & 31, ty = threadIdx.x >> 5;   // 32 x 8
    const float* inE = in + (size_t)e * M * N;
    unsigned short* outE = out + (size_t)e * M * N;
#pragma unroll
    for (int i = ty; i < 32; i += 8)
        t[i][tx] = inE[(size_t)(m0 + i) * N + n0 + tx];
    __syncthreads();
#pragma unroll
    for (int i = ty; i < 32; i += 8)
        outE[(size_t)(n0 + i) * M + m0 + tx] = f2bf(t[tx][i]);
}

// ---------------- MFMA expert kernel ----------------
// block: 512 threads (8 waves). 64-token tile per (expert, tile-x) block.
// Phase 1: U,V = X*Wu/Wv  (waves split R: 32 cols each)
// Phase 2: Y = S*Wo       (waves split D: 2 chunks of 64 cols each)
__global__ __launch_bounds__(512, 2) void k_expert_mfma(
        const unsigned short* __restrict__ xb,
        const unsigned short* __restrict__ Wub,   // [E][R][D] bf16 (k-contig)
        const unsigned short* __restrict__ Wvb,   // [E][R][D]
        const unsigned short* __restrict__ Wob,   // [E][D][R] bf16 (k-contig)
        const int* __restrict__ counts,
        const int* __restrict__ offsets,
        const int* __restrict__ btok,
        const float* __restrict__ bw,
        float* __restrict__ out) {
    int e  = blockIdx.y;
    int ne = counts[e];
    int t0 = blockIdx.x * 64;
    if (t0 >= ne) return;
    int nt = min(64, ne - t0);
    int start = offsets[e] + t0;

    int tid  = threadIdx.x;
    int w    = tid >> 6;       // wave 0..7
    int lane = tid & 63;
    int m16  = lane & 15;
    int quad = lane >> 4;

    __shared__ unsigned short Xs[64][40];    // 32-k chunk, padded to 16B-aligned rows
    __shared__ unsigned short Ss[64][264];   // S tile (bf16), 16B-aligned rows
    __shared__ int   tokL[64];
    __shared__ float gwL[64];

    if (tid < 64) {
        tokL[tid] = (tid < nt) ? btok[start + tid] : btok[start];
        gwL[tid]  = (tid < nt) ? bw[start + tid] : 0.f;
    }
    __syncthreads();

    const unsigned short* WuE = Wub + (size_t)e * RR * DIM;
    const unsigned short* WvE = Wvb + (size_t)e * RR * DIM;

    f32x4 accU[4][2], accV[4][2];
    f32x4 zz = {0.f, 0.f, 0.f, 0.f};
#pragma unroll
    for (int mt = 0; mt < 4; ++mt)
#pragma unroll
        for (int ntl = 0; ntl < 2; ++ntl) { accU[mt][ntl] = zz; accV[mt][ntl] = zz; }

    for (int k0 = 0; k0 < DIM; k0 += 32) {
        __syncthreads();
        if (tid < 256) {   // stage X chunk: 64 rows x 32 bf16 (4x16B per row)
            int row = tid >> 2, seg = tid & 3;
            const unsigned short* src = xb + (size_t)tokL[row] * DIM + k0 + seg * 8;
            *(uint4*)&Xs[row][seg * 8] = *(const uint4*)src;
        }
        __syncthreads();

        bf16x8 a[4];
#pragma unroll
        for (int mt = 0; mt < 4; ++mt)
            a[mt] = *(const bf16x8*)&Xs[mt * 16 + m16][quad * 8];

        bf16x8 bu[2], bv[2];
#pragma unroll
        for (int ntl = 0; ntl < 2; ++ntl) {
            size_t ro = (size_t)(w * 32 + ntl * 16 + m16) * DIM + k0 + quad * 8;
            bu[ntl] = *(const bf16x8*)(WuE + ro);
            bv[ntl] = *(const bf16x8*)(WvE + ro);
        }
#pragma unroll
        for (int ntl = 0; ntl < 2; ++ntl)
#pragma unroll
            for (int mt = 0; mt < 4; ++mt) {
                accU[mt][ntl] = __builtin_amdgcn_mfma_f32_16x16x32_bf16(a[mt], bu[ntl], accU[mt][ntl], 0, 0, 0);
                accV[mt][ntl] = __builtin_amdgcn_mfma_f32_16x16x32_bf16(a[mt], bv[ntl], accV[mt][ntl], 0, 0, 0);
            }
    }

    // S = silu(U)*V*gate -> LDS (C-layout -> bf16 rows for A-layout reads)
    __syncthreads();
#pragma unroll
    for (int mt = 0; mt < 4; ++mt)
#pragma unroll
        for (int ntl = 0; ntl < 2; ++ntl)
#pragma unroll
            for (int reg = 0; reg < 4; ++reg) {
                int row = mt * 16 + quad * 4 + reg;
                int col = w * 32 + ntl * 16 + m16;
                float u = accU[mt][ntl][reg], v = accV[mt][ntl][reg];
                float s = (u / (1.f + __expf(-u))) * v * gwL[row];
                Ss[row][col] = f2bf(s);
            }
    __syncthreads();

    const unsigned short* WoE = Wob + (size_t)e * DIM * RR;
#pragma unroll
    for (int c = 0; c < 2; ++c) {
        int n0 = (w + c * 8) * 64;
        f32x4 acc[4][4];
#pragma unroll
        for (int mt = 0; mt < 4; ++mt)
#pragma unroll
            for (int ntl = 0; ntl < 4; ++ntl) acc[mt][ntl] = zz;

        for (int ks = 0; ks < RR; ks += 32) {
            bf16x8 a2[4];
#pragma unroll
            for (int mt = 0; mt < 4; ++mt)
                a2[mt] = *(const bf16x8*)&Ss[mt * 16 + m16][ks + quad * 8];
#pragma unroll
            for (int ntl = 0; ntl < 4; ++ntl) {
                const unsigned short* bp = WoE + (size_t)(n0 + ntl * 16 + m16) * RR + ks + quad * 8;
                bf16x8 b2 = *(const bf16x8*)bp;
#pragma unroll
                for (int mt = 0; mt < 4; ++mt)
                    acc[mt][ntl] = __builtin_amdgcn_mfma_f32_16x16x32_bf16(a2[mt], b2, acc[mt][ntl], 0, 0, 0);
            }
        }
#pragma unroll
        for (int mt = 0; mt < 4; ++mt)
#pragma unroll
            for (int ntl = 0; ntl < 4; ++ntl)
#pragma unroll
                for (int reg = 0; reg < 4; ++reg) {
                    int row = mt * 16 + quad * 4 + reg;
                    if (row < nt)
                        atomicAdd(&out[(size_t)tokL[row] * DIM + n0 + ntl * 16 + m16],
                                  acc[mt][ntl][reg]);
                }
    }
}

// ---------------- fp32 fallback expert kernel (round-1, known-good) ----------------
#define TT 32
__global__ __launch_bounds__(256) void k_expert(const float* __restrict__ x,
                                                const float* __restrict__ Wu,
                                                const float* __restrict__ Wv,
                                                const float* __restrict__ Wo,
                                                const int* __restrict__ counts,
                                                const int* __restrict__ offsets,
                                                const int* __restrict__ btok,
                                                const float* __restrict__ bw,
                                                float* __restrict__ out) {
    int e  = blockIdx.y;
    int ne = counts[e];
    int t0 = blockIdx.x * TT;
    if (t0 >= ne) return;
    int nt = min(TT, ne - t0);
    int start = offsets[e] + t0;
    int j = threadIdx.x;

    __shared__ float xs[TT][64];
    __shared__ float sls[TT][RR];
    __shared__ int   tokL[TT];
    __shared__ float gwL[TT];

    if (j < TT) {
        if (j < nt) { tokL[j] = btok[start + j]; gwL[j] = bw[start + j]; }
        else        { tokL[j] = 0;               gwL[j] = 0.f; }
    }
    __syncthreads();

    float au[TT], av[TT];
#pragma unroll
    for (int t = 0; t < TT; ++t) { au[t] = 0.f; av[t] = 0.f; }

    const float* WuE = Wu + (size_t)e * DIM * RR;
    const float* WvE = Wv + (size_t)e * DIM * RR;

    for (int d0 = 0; d0 < DIM; d0 += 64) {
        __syncthreads();
        for (int idx = j; idx < TT * 64; idx += 256) {
            int t = idx >> 6, dd = idx & 63;
            xs[t][dd] = (t < nt) ? x[(size_t)tokL[t] * DIM + d0 + dd] : 0.f;
        }
        __syncthreads();
        for (int dd = 0; dd < 64; dd += 4) {
            float wu0 = WuE[(size_t)(d0 + dd + 0) * RR + j];
            float wu1 = WuE[(size_t)(d0 + dd + 1) * RR + j];
            float wu2 = WuE[(size_t)(d0 + dd + 2) * RR + j];
            float wu3 = WuE[(size_t)(d0 + dd + 3) * RR + j];
            float wv0 = WvE[(size_t)(d0 + dd + 0) * RR + j];
            float wv1 = WvE[(size_t)(d0 + dd + 1) * RR + j];
            float wv2 = WvE[(size_t)(d0 + dd + 2) * RR + j];
            float wv3 = WvE[(size_t)(d0 + dd + 3) * RR + j];
#pragma unroll
            for (int t = 0; t < TT; ++t) {
                float4 xv = *(const float4*)&xs[t][dd];
                au[t] += xv.x * wu0; au[t] += xv.y * wu1;
                au[t] += xv.z * wu2; au[t] += xv.w * wu3;
                av[t] += xv.x * wv0; av[t] += xv.y * wv1;
                av[t] += xv.z * wv2; av[t] += xv.w * wv3;
            }
        }
    }
    __syncthreads();
#pragma unroll
    for (int t = 0; t < TT; ++t) {
        float u = au[t], v = av[t];
        float s = (u / (1.f + __expf(-u))) * v * gwL[t];
        sls[t][j] = s;
    }
    __syncthreads();

    const float* WoE = Wo + (size_t)e * RR * DIM;
    for (int c = 0; c < 4; ++c) {
        int d = c * 256 + j;
        float y[TT];
#pragma unroll
        for (int t = 0; t < TT; ++t) y[t] = 0.f;
        for (int r = 0; r < RR; r += 4) {
            float wo0 = WoE[(size_t)(r + 0) * DIM + d];
            float wo1 = WoE[(size_t)(r + 1) * DIM + d];
            float wo2 = WoE[(size_t)(r + 2) * DIM + d];
            float wo3 = WoE[(size_t)(r + 3) * DIM + d];
#pragma unroll
            for (int t = 0; t < TT; ++t) {
                float4 sv = *(const float4*)&sls[t][r];
                y[t] += sv.x * wo0; y[t] += sv.y * wo1;
                y[t] += sv.z * wo2; y[t] += sv.w * wo3;
            }
        }
        for (int t = 0; t < nt; ++t) {
            atomicAdd(&out[(size_t)tokL[t] * DIM + d], y[t]);
        }
    }
}

extern "C" void kernel_launch(void* const* d_in, const int* in_sizes, int n_in,
                              void* d_out, int out_size, void* d_ws, size_t ws_size,
                              hipStream_t stream) {
    const float* x  = (const float*)d_in[0];
    const float* gw = (const float*)d_in[1];
    const float* Wu = (const float*)d_in[2];
    const float* Wv = (const float*)d_in[3];
    const float* Wo = (const float*)d_in[4];
    float* out = (float*)d_out;

    int*   wsi     = (int*)d_ws;
    int*   counts  = wsi + 0;
    int*   offsets = wsi + 8;
    int*   fill    = wsi + 16;
    int*   topi    = wsi + 32;
    float* topw    = (float*)(wsi + 32 + 16384);
    int*   btok    = wsi + 32 + 32768;
    float* bw      = (float*)(wsi + 32 + 49152);
    // routing region ends at byte 4*(32+65536) = 262,272.

    hipMemsetAsync(d_ws, 0, 128, stream);
    hipMemsetAsync(d_out, 0, (size_t)BN * DIM * sizeof(float), stream);

    // bf16 scratch starts at 320 KB — PAST the routing region (round-2 bug:
    // xb at 256 KB overlapped the last 128 bytes of bw and clobbered gate
    // weights after k_fill ran).
    const size_t off_xb  = 327680;
    const size_t off_wub = off_xb  + (size_t)BN * DIM * 2;      // 16 MB
    const size_t off_wvb = off_wub + (size_t)NE * RR * DIM * 2; // 4 MB
    const size_t off_wob = off_wvb + (size_t)NE * RR * DIM * 2; // 4 MB
    const size_t need    = off_wob + (size_t)NE * DIM * RR * 2; // + 4 MB

    k_router<<<dim3(BN / 4), 256, 0, stream>>>(x, gw, counts, topi, topw);
    k_scan<<<1, 64, 0, stream>>>(counts, offsets, fill);
    k_fill<<<dim3(BN * 2 / 256), 256, 0, stream>>>(topi, topw, offsets, fill, btok, bw);

    if (ws_size >= need) {
        unsigned short* xb  = (unsigned short*)((char*)d_ws + off_xb);
        unsigned short* Wub = (unsigned short*)((char*)d_ws + off_wub);
        unsigned short* Wvb = (unsigned short*)((char*)d_ws + off_wvb);
        unsigned short* Wob = (unsigned short*)((char*)d_ws + off_wob);

        k_cvt_x<<<dim3(BN * DIM / 8 / 256), 256, 0, stream>>>(x, xb);
        k_cvt_w<<<dim3(RR / 32, DIM / 32, NE), 256, 0, stream>>>(Wu, Wub, DIM, RR);
        k_cvt_w<<<dim3(RR / 32, DIM / 32, NE), 256, 0, stream>>>(Wv, Wvb, DIM, RR);
        k_cvt_w<<<dim3(DIM / 32, RR / 32, NE), 256, 0, stream>>>(Wo, Wob, RR, DIM);

        k_expert_mfma<<<dim3(BN / 64, NE), 512, 0, stream>>>(xb, Wub, Wvb, Wob,
                                                             counts, offsets, btok, bw, out);
    } else {
        k_expert<<<dim3(BN / TT, NE), 256, 0, stream>>>(x, Wu, Wv, Wo, counts, offsets,
                                                        btok, bw, out);
    }
}

// Round 4
// 553.086 us; speedup vs baseline: 2.4026x; 1.0221x over previous
//
#include <hip/hip_runtime.h>
#include <math.h>

#define BN 8192      // B*N tokens
#define DIM 1024     // D
#define NE 8         // E experts
#define RR 256       // R

using bf16x8 = __attribute__((ext_vector_type(8))) short;
using f32x4  = __attribute__((ext_vector_type(4))) float;

__device__ inline unsigned short f2bf(float f) {
    unsigned int u = __float_as_uint(f);
    u = (u + 0x7fffu + ((u >> 16) & 1u)) >> 16;
    return (unsigned short)u;
}

// ---------------- gw transpose: [D][E] -> [E][D] fp32 ----------------
__global__ __launch_bounds__(256) void k_gwt(const float* __restrict__ gw,
                                             float* __restrict__ gwT) {
    int i = blockIdx.x * 256 + threadIdx.x;   // 8192 elements
    float v = gw[i];
    int d = i >> 3, e = i & 7;
    gwT[e * DIM + d] = v;
}

// ---------------- routing (coalesced, fp32) ----------------
__global__ __launch_bounds__(256) void k_router2(const float* __restrict__ x,
                                                 const float* __restrict__ gwT,
                                                 int* __restrict__ counts,
                                                 int* __restrict__ topi,
                                                 float* __restrict__ topw) {
    int wid  = (blockIdx.x * blockDim.x + threadIdx.x) >> 6;  // one wave per token
    int lane = threadIdx.x & 63;
    const float* xp = x + (size_t)wid * DIM + lane * 4;
    float4 acc[NE];
#pragma unroll
    for (int e = 0; e < NE; ++e) acc[e] = float4{0.f, 0.f, 0.f, 0.f};
#pragma unroll
    for (int k = 0; k < 4; ++k) {
        float4 xv = *(const float4*)(xp + k * 256);
#pragma unroll
        for (int e = 0; e < NE; ++e) {
            float4 gv = *(const float4*)(gwT + e * DIM + k * 256 + lane * 4);
            acc[e].x += xv.x * gv.x; acc[e].y += xv.y * gv.y;
            acc[e].z += xv.z * gv.z; acc[e].w += xv.w * gv.w;
        }
    }
    float lg[NE];
#pragma unroll
    for (int e = 0; e < NE; ++e)
        lg[e] = (acc[e].x + acc[e].y) + (acc[e].z + acc[e].w);
#pragma unroll
    for (int off = 32; off; off >>= 1) {
#pragma unroll
        for (int e = 0; e < NE; ++e) lg[e] += __shfl_xor(lg[e], off, 64);
    }
    if (lane == 0) {
        float best = lg[0]; int bi = 0;
#pragma unroll
        for (int e = 1; e < NE; ++e) if (lg[e] > best) { best = lg[e]; bi = e; }
        float sec = -3.4e38f; int si = 0;
#pragma unroll
        for (int e = 0; e < NE; ++e) if (e != bi && lg[e] > sec) { sec = lg[e]; si = e; }
        float p  = __expf(sec - best);
        float w0 = 1.f / (1.f + p);
        float w1 = p * w0;
        topi[wid * 2 + 0] = bi;  topw[wid * 2 + 0] = w0;
        topi[wid * 2 + 1] = si;  topw[wid * 2 + 1] = w1;
        atomicAdd(&counts[bi], 1);
        atomicAdd(&counts[si], 1);
    }
}

__global__ void k_scan(const int* __restrict__ counts, int* __restrict__ offsets,
                       int* __restrict__ fill) {
    if (threadIdx.x == 0) {
        int acc = 0;
        for (int e = 0; e < NE; ++e) { offsets[e] = acc; acc += counts[e]; }
    }
    if (threadIdx.x < NE) fill[threadIdx.x] = 0;
}

__global__ __launch_bounds__(256) void k_fill(const int* __restrict__ topi,
                                              const float* __restrict__ topw,
                                              const int* __restrict__ offsets,
                                              int* __restrict__ fill,
                                              int* __restrict__ btok,
                                              float* __restrict__ bw) {
    int i = blockIdx.x * 256 + threadIdx.x;
    if (i >= BN * 2) return;
    int e = topi[i];
    int pos = atomicAdd(&fill[e], 1);
    int slot = offsets[e] + pos;
    btok[slot] = i >> 1;
    bw[slot]   = topw[i];
}

// transpose+convert: in [E][M][N] fp32 -> out [E][N][M] bf16
__global__ __launch_bounds__(256) void k_cvt_w(const float* __restrict__ in,
                                               unsigned short* __restrict__ out,
                                               int M, int N) {
    int e  = blockIdx.z;
    int n0 = blockIdx.x * 32, m0 = blockIdx.y * 32;
    __shared__ float t[32][33];
    int tx = threadIdx.x & 31, ty = threadIdx.x >> 5;   // 32 x 8
    const float* inE = in + (size_t)e * M * N;
    unsigned short* outE = out + (size_t)e * M * N;
#pragma unroll
    for (int i = ty; i < 32; i += 8)
        t[i][tx] = inE[(size_t)(m0 + i) * N + n0 + tx];
    __syncthreads();
#pragma unroll
    for (int i = ty; i < 32; i += 8)
        outE[(size_t)(n0 + i) * M + m0 + tx] = f2bf(t[tx][i]);
}

// ---------------- MFMA expert kernel ----------------
// block: 512 threads (8 waves). 64-token tile per (expert, tile-x) block.
// Phase 1: U,V = X*Wu/Wv  (waves split R: 32 cols each)
// Phase 2: Y = S*Wo       (waves split D: 2 chunks of 64 cols each)
__global__ __launch_bounds__(512, 2) void k_expert_mfma(
        const float* __restrict__ x,              // fp32 x, converted in-kernel
        const unsigned short* __restrict__ Wub,   // [E][R][D] bf16 (k-contig)
        const unsigned short* __restrict__ Wvb,   // [E][R][D]
        const unsigned short* __restrict__ Wob,   // [E][D][R] bf16 (k-contig)
        const int* __restrict__ counts,
        const int* __restrict__ offsets,
        const int* __restrict__ btok,
        const float* __restrict__ bw,
        float* __restrict__ out) {
    int e  = blockIdx.y;
    int ne = counts[e];
    int t0 = blockIdx.x * 64;
    if (t0 >= ne) return;
    int nt = min(64, ne - t0);
    int start = offsets[e] + t0;

    int tid  = threadIdx.x;
    int w    = tid >> 6;       // wave 0..7
    int lane = tid & 63;
    int m16  = lane & 15;
    int quad = lane >> 4;

    __shared__ unsigned short Xs[64][40];    // 32-k chunk, padded rows (80B stride)
    __shared__ unsigned short Ss[64][264];   // S tile (bf16), 16B-aligned rows
    __shared__ int   tokL[64];
    __shared__ float gwL[64];

    if (tid < 64) {
        tokL[tid] = (tid < nt) ? btok[start + tid] : btok[start];
        gwL[tid]  = (tid < nt) ? bw[start + tid] : 0.f;
    }
    __syncthreads();

    const unsigned short* WuE = Wub + (size_t)e * RR * DIM;
    const unsigned short* WvE = Wvb + (size_t)e * RR * DIM;

    f32x4 accU[4][2], accV[4][2];
    f32x4 zz = {0.f, 0.f, 0.f, 0.f};
#pragma unroll
    for (int mt = 0; mt < 4; ++mt)
#pragma unroll
        for (int ntl = 0; ntl < 2; ++ntl) { accU[mt][ntl] = zz; accV[mt][ntl] = zz; }

    int srow = tid >> 3, sseg = tid & 7;     // 64 rows x 8 float4-segments
    const float* srcbase = x + (size_t)tokL[srow] * DIM + sseg * 4;

    for (int k0 = 0; k0 < DIM; k0 += 32) {
        __syncthreads();
        {   // stage X chunk: 64 rows x 32 fp32 -> bf16 in LDS
            float4 f = *(const float4*)(srcbase + k0);
            ushort4 us = { f2bf(f.x), f2bf(f.y), f2bf(f.z), f2bf(f.w) };
            *(ushort4*)&Xs[srow][sseg * 4] = us;
        }
        __syncthreads();

        bf16x8 a[4];
#pragma unroll
        for (int mt = 0; mt < 4; ++mt)
            a[mt] = *(const bf16x8*)&Xs[mt * 16 + m16][quad * 8];

        bf16x8 bu[2], bv[2];
#pragma unroll
        for (int ntl = 0; ntl < 2; ++ntl) {
            size_t ro = (size_t)(w * 32 + ntl * 16 + m16) * DIM + k0 + quad * 8;
            bu[ntl] = *(const bf16x8*)(WuE + ro);
            bv[ntl] = *(const bf16x8*)(WvE + ro);
        }
#pragma unroll
        for (int ntl = 0; ntl < 2; ++ntl)
#pragma unroll
            for (int mt = 0; mt < 4; ++mt) {
                accU[mt][ntl] = __builtin_amdgcn_mfma_f32_16x16x32_bf16(a[mt], bu[ntl], accU[mt][ntl], 0, 0, 0);
                accV[mt][ntl] = __builtin_amdgcn_mfma_f32_16x16x32_bf16(a[mt], bv[ntl], accV[mt][ntl], 0, 0, 0);
            }
    }

    // S = silu(U)*V*gate -> LDS (C-layout -> bf16 rows for A-layout reads)
    __syncthreads();
#pragma unroll
    for (int mt = 0; mt < 4; ++mt)
#pragma unroll
        for (int ntl = 0; ntl < 2; ++ntl)
#pragma unroll
            for (int reg = 0; reg < 4; ++reg) {
                int row = mt * 16 + quad * 4 + reg;
                int col = w * 32 + ntl * 16 + m16;
                float u = accU[mt][ntl][reg], v = accV[mt][ntl][reg];
                float s = (u / (1.f + __expf(-u))) * v * gwL[row];
                Ss[row][col] = f2bf(s);
            }
    __syncthreads();

    const unsigned short* WoE = Wob + (size_t)e * DIM * RR;
#pragma unroll
    for (int c = 0; c < 2; ++c) {
        int n0 = (w + c * 8) * 64;
        f32x4 acc[4][4];
#pragma unroll
        for (int mt = 0; mt < 4; ++mt)
#pragma unroll
            for (int ntl = 0; ntl < 4; ++ntl) acc[mt][ntl] = zz;

        for (int ks = 0; ks < RR; ks += 32) {
            bf16x8 a2[4];
#pragma unroll
            for (int mt = 0; mt < 4; ++mt)
                a2[mt] = *(const bf16x8*)&Ss[mt * 16 + m16][ks + quad * 8];
#pragma unroll
            for (int ntl = 0; ntl < 4; ++ntl) {
                const unsigned short* bp = WoE + (size_t)(n0 + ntl * 16 + m16) * RR + ks + quad * 8;
                bf16x8 b2 = *(const bf16x8*)bp;
#pragma unroll
                for (int mt = 0; mt < 4; ++mt)
                    acc[mt][ntl] = __builtin_amdgcn_mfma_f32_16x16x32_bf16(a2[mt], b2, acc[mt][ntl], 0, 0, 0);
            }
        }
#pragma unroll
        for (int mt = 0; mt < 4; ++mt)
#pragma unroll
            for (int ntl = 0; ntl < 4; ++ntl)
#pragma unroll
                for (int reg = 0; reg < 4; ++reg) {
                    int row = mt * 16 + quad * 4 + reg;
                    if (row < nt)
                        atomicAdd(&out[(size_t)tokL[row] * DIM + n0 + ntl * 16 + m16],
                                  acc[mt][ntl][reg]);
                }
    }
}

// ---------------- fp32 fallback expert kernel (round-1, known-good) ----------------
#define TT 32
__global__ __launch_bounds__(256) void k_expert(const float* __restrict__ x,
                                                const float* __restrict__ Wu,
                                                const float* __restrict__ Wv,
                                                const float* __restrict__ Wo,
                                                const int* __restrict__ counts,
                                                const int* __restrict__ offsets,
                                                const int* __restrict__ btok,
                                                const float* __restrict__ bw,
                                                float* __restrict__ out) {
    int e  = blockIdx.y;
    int ne = counts[e];
    int t0 = blockIdx.x * TT;
    if (t0 >= ne) return;
    int nt = min(TT, ne - t0);
    int start = offsets[e] + t0;
    int j = threadIdx.x;

    __shared__ float xs[TT][64];
    __shared__ float sls[TT][RR];
    __shared__ int   tokL[TT];
    __shared__ float gwL[TT];

    if (j < TT) {
        if (j < nt) { tokL[j] = btok[start + j]; gwL[j] = bw[start + j]; }
        else        { tokL[j] = 0;               gwL[j] = 0.f; }
    }
    __syncthreads();

    float au[TT], av[TT];
#pragma unroll
    for (int t = 0; t < TT; ++t) { au[t] = 0.f; av[t] = 0.f; }

    const float* WuE = Wu + (size_t)e * DIM * RR;
    const float* WvE = Wv + (size_t)e * DIM * RR;

    for (int d0 = 0; d0 < DIM; d0 += 64) {
        __syncthreads();
        for (int idx = j; idx < TT * 64; idx += 256) {
            int t = idx >> 6, dd = idx & 63;
            xs[t][dd] = (t < nt) ? x[(size_t)tokL[t] * DIM + d0 + dd] : 0.f;
        }
        __syncthreads();
        for (int dd = 0; dd < 64; dd += 4) {
            float wu0 = WuE[(size_t)(d0 + dd + 0) * RR + j];
            float wu1 = WuE[(size_t)(d0 + dd + 1) * RR + j];
            float wu2 = WuE[(size_t)(d0 + dd + 2) * RR + j];
            float wu3 = WuE[(size_t)(d0 + dd + 3) * RR + j];
            float wv0 = WvE[(size_t)(d0 + dd + 0) * RR + j];
            float wv1 = WvE[(size_t)(d0 + dd + 1) * RR + j];
            float wv2 = WvE[(size_t)(d0 + dd + 2) * RR + j];
            float wv3 = WvE[(size_t)(d0 + dd + 3) * RR + j];
#pragma unroll
            for (int t = 0; t < TT; ++t) {
                float4 xv = *(const float4*)&xs[t][dd];
                au[t] += xv.x * wu0; au[t] += xv.y * wu1;
                au[t] += xv.z * wu2; au[t] += xv.w * wu3;
                av[t] += xv.x * wv0; av[t] += xv.y * wv1;
                av[t] += xv.z * wv2; av[t] += xv.w * wv3;
            }
        }
    }
    __syncthreads();
#pragma unroll
    for (int t = 0; t < TT; ++t) {
        float u = au[t], v = av[t];
        float s = (u / (1.f + __expf(-u))) * v * gwL[t];
        sls[t][j] = s;
    }
    __syncthreads();

    const float* WoE = Wo + (size_t)e * RR * DIM;
    for (int c = 0; c < 4; ++c) {
        int d = c * 256 + j;
        float y[TT];
#pragma unroll
        for (int t = 0; t < TT; ++t) y[t] = 0.f;
        for (int r = 0; r < RR; r += 4) {
            float wo0 = WoE[(size_t)(r + 0) * DIM + d];
            float wo1 = WoE[(size_t)(r + 1) * DIM + d];
            float wo2 = WoE[(size_t)(r + 2) * DIM + d];
            float wo3 = WoE[(size_t)(r + 3) * DIM + d];
#pragma unroll
            for (int t = 0; t < TT; ++t) {
                float4 sv = *(const float4*)&sls[t][r];
                y[t] += sv.x * wo0; y[t] += sv.y * wo1;
                y[t] += sv.z * wo2; y[t] += sv.w * wo3;
            }
        }
        for (int t = 0; t < nt; ++t) {
            atomicAdd(&out[(size_t)tokL[t] * DIM + d], y[t]);
        }
    }
}

extern "C" void kernel_launch(void* const* d_in, const int* in_sizes, int n_in,
                              void* d_out, int out_size, void* d_ws, size_t ws_size,
                              hipStream_t stream) {
    const float* x  = (const float*)d_in[0];
    const float* gw = (const float*)d_in[1];
    const float* Wu = (const float*)d_in[2];
    const float* Wv = (const float*)d_in[3];
    const float* Wo = (const float*)d_in[4];
    float* out = (float*)d_out;

    int*   wsi     = (int*)d_ws;
    int*   counts  = wsi + 0;
    int*   offsets = wsi + 8;
    int*   fill    = wsi + 16;
    int*   topi    = wsi + 32;
    float* topw    = (float*)(wsi + 32 + 16384);
    int*   btok    = wsi + 32 + 32768;
    float* bw      = (float*)(wsi + 32 + 49152);
    // routing region ends at byte 4*(32+65536) = 262,272.
    float* gwT     = (float*)((char*)d_ws + 262144 + 4096);   // 32 KB, ends < 299 KB

    hipMemsetAsync(d_ws, 0, 128, stream);
    hipMemsetAsync(d_out, 0, (size_t)BN * DIM * sizeof(float), stream);

    // bf16 weight scratch starts at 320 KB (past routing region + gwT)
    const size_t off_wub = 327680;
    const size_t off_wvb = off_wub + (size_t)NE * RR * DIM * 2; // 4 MB
    const size_t off_wob = off_wvb + (size_t)NE * RR * DIM * 2; // 4 MB
    const size_t need    = off_wob + (size_t)NE * DIM * RR * 2; // + 4 MB

    k_gwt<<<dim3(DIM * NE / 256), 256, 0, stream>>>(gw, gwT);
    k_router2<<<dim3(BN / 4), 256, 0, stream>>>(x, gwT, counts, topi, topw);
    k_scan<<<1, 64, 0, stream>>>(counts, offsets, fill);
    k_fill<<<dim3(BN * 2 / 256), 256, 0, stream>>>(topi, topw, offsets, fill, btok, bw);

    if (ws_size >= need) {
        unsigned short* Wub = (unsigned short*)((char*)d_ws + off_wub);
        unsigned short* Wvb = (unsigned short*)((char*)d_ws + off_wvb);
        unsigned short* Wob = (unsigned short*)((char*)d_ws + off_wob);

        k_cvt_w<<<dim3(RR / 32, DIM / 32, NE), 256, 0, stream>>>(Wu, Wub, DIM, RR);
        k_cvt_w<<<dim3(RR / 32, DIM / 32, NE), 256, 0, stream>>>(Wv, Wvb, DIM, RR);
        k_cvt_w<<<dim3(DIM / 32, RR / 32, NE), 256, 0, stream>>>(Wo, Wob, RR, DIM);

        k_expert_mfma<<<dim3(BN / 64, NE), 512, 0, stream>>>(x, Wub, Wvb, Wob,
                                                             counts, offsets, btok, bw, out);
    } else {
        k_expert<<<dim3(BN / TT, NE), 256, 0, stream>>>(x, Wu, Wv, Wo, counts, offsets,
                                                        btok, bw, out);
    }
}

// Round 5
// 323.462 us; speedup vs baseline: 4.1082x; 1.7099x over previous
//
#include <hip/hip_runtime.h>
#include <math.h>

#define BN 8192      // B*N tokens
#define DIM 1024     // D
#define NE 8         // E experts
#define RR 256       // R

using bf16x8 = __attribute__((ext_vector_type(8))) short;
using f32x4  = __attribute__((ext_vector_type(4))) float;

__device__ inline unsigned short f2bf(float f) {
    unsigned int u = __float_as_uint(f);
    u = (u + 0x7fffu + ((u >> 16) & 1u)) >> 16;
    return (unsigned short)u;
}

// ---------------- gw transpose: [D][E] -> [E][D] fp32 ----------------
__global__ __launch_bounds__(256) void k_gwt(const float* __restrict__ gw,
                                             float* __restrict__ gwT) {
    int i = blockIdx.x * 256 + threadIdx.x;   // 8192 elements
    float v = gw[i];
    int d = i >> 3, e = i & 7;
    gwT[e * DIM + d] = v;
}

// ---------------- routing (coalesced, fp32, NO atomics) ----------------
__global__ __launch_bounds__(256) void k_router3(const float* __restrict__ x,
                                                 const float* __restrict__ gwT,
                                                 int* __restrict__ topi,
                                                 float* __restrict__ topw) {
    int wid  = (blockIdx.x * blockDim.x + threadIdx.x) >> 6;  // one wave per token
    int lane = threadIdx.x & 63;
    const float* xp = x + (size_t)wid * DIM + lane * 4;
    float4 acc[NE];
#pragma unroll
    for (int e = 0; e < NE; ++e) acc[e] = float4{0.f, 0.f, 0.f, 0.f};
#pragma unroll
    for (int k = 0; k < 4; ++k) {
        float4 xv = *(const float4*)(xp + k * 256);
#pragma unroll
        for (int e = 0; e < NE; ++e) {
            float4 gv = *(const float4*)(gwT + e * DIM + k * 256 + lane * 4);
            acc[e].x += xv.x * gv.x; acc[e].y += xv.y * gv.y;
            acc[e].z += xv.z * gv.z; acc[e].w += xv.w * gv.w;
        }
    }
    float lg[NE];
#pragma unroll
    for (int e = 0; e < NE; ++e)
        lg[e] = (acc[e].x + acc[e].y) + (acc[e].z + acc[e].w);
#pragma unroll
    for (int off = 32; off; off >>= 1) {
#pragma unroll
        for (int e = 0; e < NE; ++e) lg[e] += __shfl_xor(lg[e], off, 64);
    }
    if (lane == 0) {
        float best = lg[0]; int bi = 0;
#pragma unroll
        for (int e = 1; e < NE; ++e) if (lg[e] > best) { best = lg[e]; bi = e; }
        float sec = -3.4e38f; int si = 0;
#pragma unroll
        for (int e = 0; e < NE; ++e) if (e != bi && lg[e] > sec) { sec = lg[e]; si = e; }
        float p  = __expf(sec - best);
        float w0 = 1.f / (1.f + p);
        float w1 = p * w0;
        topi[wid * 2 + 0] = bi;  topw[wid * 2 + 0] = w0;
        topi[wid * 2 + 1] = si;  topw[wid * 2 + 1] = w1;
    }
}

// ---------------- counts + offsets in one tiny kernel (no global atomics) ----
__global__ __launch_bounds__(256) void k_count_scan(const int* __restrict__ topi,
                                                    int* __restrict__ counts,
                                                    int* __restrict__ offsets,
                                                    int* __restrict__ fill) {
    __shared__ int sh[256 * NE];
    int tid = threadIdx.x;
    int c[NE];
#pragma unroll
    for (int j = 0; j < NE; ++j) c[j] = 0;
    for (int i = tid; i < BN * 2; i += 256) {
        int e = topi[i];
#pragma unroll
        for (int j = 0; j < NE; ++j) c[j] += (e == j);
    }
#pragma unroll
    for (int j = 0; j < NE; ++j) sh[tid * NE + j] = c[j];
    __syncthreads();
    for (int s = 128; s > 0; s >>= 1) {
        if (tid < s) {
#pragma unroll
            for (int j = 0; j < NE; ++j) sh[tid * NE + j] += sh[(tid + s) * NE + j];
        }
        __syncthreads();
    }
    if (tid == 0) {
        int acc = 0;
        for (int j = 0; j < NE; ++j) { counts[j] = sh[j]; offsets[j] = acc; acc += sh[j]; }
    }
    if (tid < NE) fill[tid] = 0;
}

// ---------------- bucket fill: per-block aggregated atomics (8/block) -------
__global__ __launch_bounds__(256) void k_fill2(const int* __restrict__ topi,
                                               const float* __restrict__ topw,
                                               const int* __restrict__ offsets,
                                               int* __restrict__ fill,
                                               int* __restrict__ btok,
                                               float* __restrict__ bw) {
    int tid = threadIdx.x;
    int i = blockIdx.x * 256 + tid;          // grid exactly covers BN*2
    int w = tid >> 6, lane = tid & 63;
    int e = topi[i];
    float wt = topw[i];

    __shared__ int waveCnt[4][NE];
    __shared__ int wavePre[4][NE];
    __shared__ int baseSh[NE];

    int myrank = 0;
    unsigned long long lt = (1ull << lane) - 1ull;
#pragma unroll
    for (int j = 0; j < NE; ++j) {
        unsigned long long m = __ballot(e == j);
        if (e == j) myrank = __popcll(m & lt);
        if (lane == 0) waveCnt[w][j] = __popcll(m);
    }
    __syncthreads();
    if (tid < NE) {
        int j = tid, acc = 0;
#pragma unroll
        for (int ww = 0; ww < 4; ++ww) { wavePre[ww][j] = acc; acc += waveCnt[ww][j]; }
        baseSh[j] = atomicAdd(&fill[j], acc);
    }
    __syncthreads();
    int slot = offsets[e] + baseSh[e] + wavePre[w][e] + myrank;
    btok[slot] = i >> 1;
    bw[slot]   = wt;
}

// transpose+convert: in [E][M][N] fp32 -> out [E][N][M] bf16
__global__ __launch_bounds__(256) void k_cvt_w(const float* __restrict__ in,
                                               unsigned short* __restrict__ out,
                                               int M, int N) {
    int e  = blockIdx.z;
    int n0 = blockIdx.x * 32, m0 = blockIdx.y * 32;
    __shared__ float t[32][33];
    int tx = threadIdx.x & 31, ty = threadIdx.x >> 5;   // 32 x 8
    const float* inE = in + (size_t)e * M * N;
    unsigned short* outE = out + (size_t)e * M * N;
#pragma unroll
    for (int i = ty; i < 32; i += 8)
        t[i][tx] = inE[(size_t)(m0 + i) * N + n0 + tx];
    __syncthreads();
#pragma unroll
    for (int i = ty; i < 32; i += 8)
        outE[(size_t)(n0 + i) * M + m0 + tx] = f2bf(t[tx][i]);
}

// ---------------- MFMA expert kernel (unchanged from round 4) ----------------
__global__ __launch_bounds__(512, 2) void k_expert_mfma(
        const float* __restrict__ x,              // fp32 x, converted in-kernel
        const unsigned short* __restrict__ Wub,   // [E][R][D] bf16 (k-contig)
        const unsigned short* __restrict__ Wvb,   // [E][R][D]
        const unsigned short* __restrict__ Wob,   // [E][D][R] bf16 (k-contig)
        const int* __restrict__ counts,
        const int* __restrict__ offsets,
        const int* __restrict__ btok,
        const float* __restrict__ bw,
        float* __restrict__ out) {
    int e  = blockIdx.y;
    int ne = counts[e];
    int t0 = blockIdx.x * 64;
    if (t0 >= ne) return;
    int nt = min(64, ne - t0);
    int start = offsets[e] + t0;

    int tid  = threadIdx.x;
    int w    = tid >> 6;       // wave 0..7
    int lane = tid & 63;
    int m16  = lane & 15;
    int quad = lane >> 4;

    __shared__ unsigned short Xs[64][40];    // 32-k chunk, padded rows (80B stride)
    __shared__ unsigned short Ss[64][264];   // S tile (bf16), 16B-aligned rows
    __shared__ int   tokL[64];
    __shared__ float gwL[64];

    if (tid < 64) {
        tokL[tid] = (tid < nt) ? btok[start + tid] : btok[start];
        gwL[tid]  = (tid < nt) ? bw[start + tid] : 0.f;
    }
    __syncthreads();

    const unsigned short* WuE = Wub + (size_t)e * RR * DIM;
    const unsigned short* WvE = Wvb + (size_t)e * RR * DIM;

    f32x4 accU[4][2], accV[4][2];
    f32x4 zz = {0.f, 0.f, 0.f, 0.f};
#pragma unroll
    for (int mt = 0; mt < 4; ++mt)
#pragma unroll
        for (int ntl = 0; ntl < 2; ++ntl) { accU[mt][ntl] = zz; accV[mt][ntl] = zz; }

    int srow = tid >> 3, sseg = tid & 7;     // 64 rows x 8 float4-segments
    const float* srcbase = x + (size_t)tokL[srow] * DIM + sseg * 4;

    for (int k0 = 0; k0 < DIM; k0 += 32) {
        __syncthreads();
        {   // stage X chunk: 64 rows x 32 fp32 -> bf16 in LDS
            float4 f = *(const float4*)(srcbase + k0);
            ushort4 us = { f2bf(f.x), f2bf(f.y), f2bf(f.z), f2bf(f.w) };
            *(ushort4*)&Xs[srow][sseg * 4] = us;
        }
        __syncthreads();

        bf16x8 a[4];
#pragma unroll
        for (int mt = 0; mt < 4; ++mt)
            a[mt] = *(const bf16x8*)&Xs[mt * 16 + m16][quad * 8];

        bf16x8 bu[2], bv[2];
#pragma unroll
        for (int ntl = 0; ntl < 2; ++ntl) {
            size_t ro = (size_t)(w * 32 + ntl * 16 + m16) * DIM + k0 + quad * 8;
            bu[ntl] = *(const bf16x8*)(WuE + ro);
            bv[ntl] = *(const bf16x8*)(WvE + ro);
        }
#pragma unroll
        for (int ntl = 0; ntl < 2; ++ntl)
#pragma unroll
            for (int mt = 0; mt < 4; ++mt) {
                accU[mt][ntl] = __builtin_amdgcn_mfma_f32_16x16x32_bf16(a[mt], bu[ntl], accU[mt][ntl], 0, 0, 0);
                accV[mt][ntl] = __builtin_amdgcn_mfma_f32_16x16x32_bf16(a[mt], bv[ntl], accV[mt][ntl], 0, 0, 0);
            }
    }

    // S = silu(U)*V*gate -> LDS (C-layout -> bf16 rows for A-layout reads)
    __syncthreads();
#pragma unroll
    for (int mt = 0; mt < 4; ++mt)
#pragma unroll
        for (int ntl = 0; ntl < 2; ++ntl)
#pragma unroll
            for (int reg = 0; reg < 4; ++reg) {
                int row = mt * 16 + quad * 4 + reg;
                int col = w * 32 + ntl * 16 + m16;
                float u = accU[mt][ntl][reg], v = accV[mt][ntl][reg];
                float s = (u / (1.f + __expf(-u))) * v * gwL[row];
                Ss[row][col] = f2bf(s);
            }
    __syncthreads();

    const unsigned short* WoE = Wob + (size_t)e * DIM * RR;
#pragma unroll
    for (int c = 0; c < 2; ++c) {
        int n0 = (w + c * 8) * 64;
        f32x4 acc[4][4];
#pragma unroll
        for (int mt = 0; mt < 4; ++mt)
#pragma unroll
            for (int ntl = 0; ntl < 4; ++ntl) acc[mt][ntl] = zz;

        for (int ks = 0; ks < RR; ks += 32) {
            bf16x8 a2[4];
#pragma unroll
            for (int mt = 0; mt < 4; ++mt)
                a2[mt] = *(const bf16x8*)&Ss[mt * 16 + m16][ks + quad * 8];
#pragma unroll
            for (int ntl = 0; ntl < 4; ++ntl) {
                const unsigned short* bp = WoE + (size_t)(n0 + ntl * 16 + m16) * RR + ks + quad * 8;
                bf16x8 b2 = *(const bf16x8*)bp;
#pragma unroll
                for (int mt = 0; mt < 4; ++mt)
                    acc[mt][ntl] = __builtin_amdgcn_mfma_f32_16x16x32_bf16(a2[mt], b2, acc[mt][ntl], 0, 0, 0);
            }
        }
#pragma unroll
        for (int mt = 0; mt < 4; ++mt)
#pragma unroll
            for (int ntl = 0; ntl < 4; ++ntl)
#pragma unroll
                for (int reg = 0; reg < 4; ++reg) {
                    int row = mt * 16 + quad * 4 + reg;
                    if (row < nt)
                        atomicAdd(&out[(size_t)tokL[row] * DIM + n0 + ntl * 16 + m16],
                                  acc[mt][ntl][reg]);
                }
    }
}

extern "C" void kernel_launch(void* const* d_in, const int* in_sizes, int n_in,
                              void* d_out, int out_size, void* d_ws, size_t ws_size,
                              hipStream_t stream) {
    const float* x  = (const float*)d_in[0];
    const float* gw = (const float*)d_in[1];
    const float* Wu = (const float*)d_in[2];
    const float* Wv = (const float*)d_in[3];
    const float* Wo = (const float*)d_in[4];
    float* out = (float*)d_out;

    int*   wsi     = (int*)d_ws;
    int*   counts  = wsi + 0;
    int*   offsets = wsi + 8;
    int*   fill    = wsi + 16;
    int*   topi    = wsi + 32;
    float* topw    = (float*)(wsi + 32 + 16384);
    int*   btok    = wsi + 32 + 32768;
    float* bw      = (float*)(wsi + 32 + 49152);
    // routing region ends at byte 4*(32+65536) = 262,272.
    float* gwT     = (float*)((char*)d_ws + 262144 + 4096);   // 32 KB, ends < 299 KB

    hipMemsetAsync(d_out, 0, (size_t)BN * DIM * sizeof(float), stream);

    // bf16 weight scratch starts at 320 KB (past routing region + gwT)
    const size_t off_wub = 327680;
    const size_t off_wvb = off_wub + (size_t)NE * RR * DIM * 2; // 4 MB
    const size_t off_wob = off_wvb + (size_t)NE * RR * DIM * 2; // 4 MB
    const size_t need    = off_wob + (size_t)NE * DIM * RR * 2; // + 4 MB

    k_gwt<<<dim3(DIM * NE / 256), 256, 0, stream>>>(gw, gwT);
    k_router3<<<dim3(BN / 4), 256, 0, stream>>>(x, gwT, topi, topw);
    k_count_scan<<<1, 256, 0, stream>>>(topi, counts, offsets, fill);
    k_fill2<<<dim3(BN * 2 / 256), 256, 0, stream>>>(topi, topw, offsets, fill, btok, bw);

    unsigned short* Wub = (unsigned short*)((char*)d_ws + off_wub);
    unsigned short* Wvb = (unsigned short*)((char*)d_ws + off_wvb);
    unsigned short* Wob = (unsigned short*)((char*)d_ws + off_wob);

    k_cvt_w<<<dim3(RR / 32, DIM / 32, NE), 256, 0, stream>>>(Wu, Wub, DIM, RR);
    k_cvt_w<<<dim3(RR / 32, DIM / 32, NE), 256, 0, stream>>>(Wv, Wvb, DIM, RR);
    k_cvt_w<<<dim3(DIM / 32, RR / 32, NE), 256, 0, stream>>>(Wo, Wob, RR, DIM);

    k_expert_mfma<<<dim3(BN / 64, NE), 512, 0, stream>>>(x, Wub, Wvb, Wob,
                                                         counts, offsets, btok, bw, out);
}

// Round 6
// 261.746 us; speedup vs baseline: 5.0769x; 1.2358x over previous
//
#include <hip/hip_runtime.h>
#include <math.h>

#define BN 8192      // B*N tokens
#define DIM 1024     // D
#define NE 8         // E experts
#define RR 256       // R

using bf16x8 = __attribute__((ext_vector_type(8))) short;
using f32x4  = __attribute__((ext_vector_type(4))) float;

__device__ inline unsigned short f2bf(float f) {
    unsigned int u = __float_as_uint(f);
    u = (u + 0x7fffu + ((u >> 16) & 1u)) >> 16;
    return (unsigned short)u;
}

// ---------------- gw transpose: [D][E] -> [E][D] fp32 ----------------
__global__ __launch_bounds__(256) void k_gwt(const float* __restrict__ gw,
                                             float* __restrict__ gwT) {
    int i = blockIdx.x * 256 + threadIdx.x;   // 8192 elements
    float v = gw[i];
    int d = i >> 3, e = i & 7;
    gwT[e * DIM + d] = v;
}

// ---------------- routing (coalesced, fp32, NO atomics) + x->bf16 ----------
__global__ __launch_bounds__(256) void k_router3(const float* __restrict__ x,
                                                 const float* __restrict__ gwT,
                                                 int* __restrict__ topi,
                                                 float* __restrict__ topw,
                                                 unsigned short* __restrict__ xb) {
    int wid  = (blockIdx.x * blockDim.x + threadIdx.x) >> 6;  // one wave per token
    int lane = threadIdx.x & 63;
    const float* xp = x + (size_t)wid * DIM + lane * 4;
    unsigned short* xbp = xb + (size_t)wid * DIM + lane * 4;
    float4 acc[NE];
#pragma unroll
    for (int e = 0; e < NE; ++e) acc[e] = float4{0.f, 0.f, 0.f, 0.f};
#pragma unroll
    for (int k = 0; k < 4; ++k) {
        float4 xv = *(const float4*)(xp + k * 256);
        ushort4 us = { f2bf(xv.x), f2bf(xv.y), f2bf(xv.z), f2bf(xv.w) };
        *(ushort4*)(xbp + k * 256) = us;
#pragma unroll
        for (int e = 0; e < NE; ++e) {
            float4 gv = *(const float4*)(gwT + e * DIM + k * 256 + lane * 4);
            acc[e].x += xv.x * gv.x; acc[e].y += xv.y * gv.y;
            acc[e].z += xv.z * gv.z; acc[e].w += xv.w * gv.w;
        }
    }
    float lg[NE];
#pragma unroll
    for (int e = 0; e < NE; ++e)
        lg[e] = (acc[e].x + acc[e].y) + (acc[e].z + acc[e].w);
#pragma unroll
    for (int off = 32; off; off >>= 1) {
#pragma unroll
        for (int e = 0; e < NE; ++e) lg[e] += __shfl_xor(lg[e], off, 64);
    }
    if (lane == 0) {
        float best = lg[0]; int bi = 0;
#pragma unroll
        for (int e = 1; e < NE; ++e) if (lg[e] > best) { best = lg[e]; bi = e; }
        float sec = -3.4e38f; int si = 0;
#pragma unroll
        for (int e = 0; e < NE; ++e) if (e != bi && lg[e] > sec) { sec = lg[e]; si = e; }
        float p  = __expf(sec - best);
        float w0 = 1.f / (1.f + p);
        float w1 = p * w0;
        topi[wid * 2 + 0] = bi;  topw[wid * 2 + 0] = w0;
        topi[wid * 2 + 1] = si;  topw[wid * 2 + 1] = w1;
    }
}

// ---------------- counts + offsets in one tiny kernel (no global atomics) ----
__global__ __launch_bounds__(256) void k_count_scan(const int* __restrict__ topi,
                                                    int* __restrict__ counts,
                                                    int* __restrict__ offsets,
                                                    int* __restrict__ fill) {
    __shared__ int sh[256 * NE];
    int tid = threadIdx.x;
    int c[NE];
#pragma unroll
    for (int j = 0; j < NE; ++j) c[j] = 0;
    for (int i = tid; i < BN * 2; i += 256) {
        int e = topi[i];
#pragma unroll
        for (int j = 0; j < NE; ++j) c[j] += (e == j);
    }
#pragma unroll
    for (int j = 0; j < NE; ++j) sh[tid * NE + j] = c[j];
    __syncthreads();
    for (int s = 128; s > 0; s >>= 1) {
        if (tid < s) {
#pragma unroll
            for (int j = 0; j < NE; ++j) sh[tid * NE + j] += sh[(tid + s) * NE + j];
        }
        __syncthreads();
    }
    if (tid == 0) {
        int acc = 0;
        for (int j = 0; j < NE; ++j) { counts[j] = sh[j]; offsets[j] = acc; acc += sh[j]; }
    }
    if (tid < NE) fill[tid] = 0;
}

// ---------------- bucket fill: per-block aggregated atomics (8/block) -------
__global__ __launch_bounds__(256) void k_fill2(const int* __restrict__ topi,
                                               const float* __restrict__ topw,
                                               const int* __restrict__ offsets,
                                               int* __restrict__ fill,
                                               int* __restrict__ btok,
                                               float* __restrict__ bw,
                                               int* __restrict__ slotOf) {
    int tid = threadIdx.x;
    int i = blockIdx.x * 256 + tid;          // grid exactly covers BN*2
    int w = tid >> 6, lane = tid & 63;
    int e = topi[i];
    float wt = topw[i];

    __shared__ int waveCnt[4][NE];
    __shared__ int wavePre[4][NE];
    __shared__ int baseSh[NE];

    int myrank = 0;
    unsigned long long lt = (1ull << lane) - 1ull;
#pragma unroll
    for (int j = 0; j < NE; ++j) {
        unsigned long long m = __ballot(e == j);
        if (e == j) myrank = __popcll(m & lt);
        if (lane == 0) waveCnt[w][j] = __popcll(m);
    }
    __syncthreads();
    if (tid < NE) {
        int j = tid, acc = 0;
#pragma unroll
        for (int ww = 0; ww < 4; ++ww) { wavePre[ww][j] = acc; acc += waveCnt[ww][j]; }
        baseSh[j] = atomicAdd(&fill[j], acc);
    }
    __syncthreads();
    int slot = offsets[e] + baseSh[e] + wavePre[w][e] + myrank;
    btok[slot]   = i >> 1;
    bw[slot]     = wt;
    slotOf[i]    = slot;
}

// transpose+convert: in [E][M][N] fp32 -> out [E][N][M] bf16
__global__ __launch_bounds__(256) void k_cvt_w(const float* __restrict__ in,
                                               unsigned short* __restrict__ out,
                                               int M, int N) {
    int e  = blockIdx.z;
    int n0 = blockIdx.x * 32, m0 = blockIdx.y * 32;
    __shared__ float t[32][33];
    int tx = threadIdx.x & 31, ty = threadIdx.x >> 5;   // 32 x 8
    const float* inE = in + (size_t)e * M * N;
    unsigned short* outE = out + (size_t)e * M * N;
#pragma unroll
    for (int i = ty; i < 32; i += 8)
        t[i][tx] = inE[(size_t)(m0 + i) * N + n0 + tx];
    __syncthreads();
#pragma unroll
    for (int i = ty; i < 32; i += 8)
        outE[(size_t)(n0 + i) * M + m0 + tx] = f2bf(t[tx][i]);
}

// ---------------- MFMA expert kernel (pipelined) ----------------
// 1-D grid: expert = bid & 7 (XCD affinity), tile = bid >> 3 (64 tokens).
// 512 threads = 8 waves. BK=64 double-buffered Xs, B-frag register prefetch.
// Epilogue: non-atomic store to ybuf[slot][*] (or atomicAdd fallback).
__global__ __launch_bounds__(512, 2) void k_expert_mfma(
        const unsigned short* __restrict__ xb,    // [BN][D] bf16
        const unsigned short* __restrict__ Wub,   // [E][R][D] bf16 (k-contig)
        const unsigned short* __restrict__ Wvb,   // [E][R][D]
        const unsigned short* __restrict__ Wob,   // [E][D][R] bf16 (k-contig)
        const int* __restrict__ counts,
        const int* __restrict__ offsets,
        const int* __restrict__ btok,
        const float* __restrict__ bw,
        float* __restrict__ ybuf,                 // [slots][D] fp32, or null
        float* __restrict__ out) {
    int e  = blockIdx.x & 7;
    int ne = counts[e];
    int t0 = (blockIdx.x >> 3) * 64;
    if (t0 >= ne) return;
    int nt = min(64, ne - t0);
    int start = offsets[e] + t0;

    int tid  = threadIdx.x;
    int w    = tid >> 6;       // wave 0..7
    int lane = tid & 63;
    int m16  = lane & 15;
    int quad = lane >> 4;

    __shared__ unsigned short Xs[2][64][72];   // 64-k chunk, dbuf; stride 144B (2-way only)
    __shared__ unsigned short Ss[64][264];     // S tile (bf16)
    __shared__ int   tokL[64];
    __shared__ float gwL[64];

    if (tid < 64) {
        tokL[tid] = (tid < nt) ? btok[start + tid] : btok[start];
        gwL[tid]  = (tid < nt) ? bw[start + tid] : 0.f;
    }
    __syncthreads();

    const unsigned short* WuE = Wub + (size_t)e * RR * DIM;
    const unsigned short* WvE = Wvb + (size_t)e * RR * DIM;

    f32x4 accU[4][2], accV[4][2];
    f32x4 zz = {0.f, 0.f, 0.f, 0.f};
#pragma unroll
    for (int mt = 0; mt < 4; ++mt)
#pragma unroll
        for (int ntl = 0; ntl < 2; ++ntl) { accU[mt][ntl] = zz; accV[mt][ntl] = zz; }

    int srow = tid >> 3, sseg = tid & 7;     // 64 rows x 8 x 16B segments
    const unsigned short* srcbase = xb + (size_t)tokL[srow] * DIM + sseg * 8;

    // prologue: chunk 0 -> Xs[0]; prefetch chunk 1 to regs; B-frags for kt=0
    uint4 xreg = *(const uint4*)(srcbase);
    *(uint4*)&Xs[0][srow][sseg * 8] = xreg;
    xreg = *(const uint4*)(srcbase + 64);

    size_t bro = (size_t)(w * 32 + m16) * DIM + quad * 8;  // ntl adds 16*DIM, s adds 32
    bf16x8 bu[2][2], bv[2][2];
#pragma unroll
    for (int ntl = 0; ntl < 2; ++ntl)
#pragma unroll
        for (int s = 0; s < 2; ++s) {
            bu[ntl][s] = *(const bf16x8*)(WuE + bro + ntl * 16 * DIM + s * 32);
            bv[ntl][s] = *(const bf16x8*)(WvE + bro + ntl * 16 * DIM + s * 32);
        }
    __syncthreads();

#pragma unroll 2
    for (int kt = 0; kt < 16; ++kt) {
        int buf = kt & 1;
        // A fragments for this 64-K chunk
        bf16x8 a[4][2];
#pragma unroll
        for (int mt = 0; mt < 4; ++mt)
#pragma unroll
            for (int s = 0; s < 2; ++s)
                a[mt][s] = *(const bf16x8*)&Xs[buf][mt * 16 + m16][s * 32 + quad * 8];

        // prefetch next B-frags
        bf16x8 nbu[2][2], nbv[2][2];
        if (kt < 15) {
            size_t nro = bro + (kt + 1) * 64;
#pragma unroll
            for (int ntl = 0; ntl < 2; ++ntl)
#pragma unroll
                for (int s = 0; s < 2; ++s) {
                    nbu[ntl][s] = *(const bf16x8*)(WuE + nro + ntl * 16 * DIM + s * 32);
                    nbv[ntl][s] = *(const bf16x8*)(WvE + nro + ntl * 16 * DIM + s * 32);
                }
        }

#pragma unroll
        for (int s = 0; s < 2; ++s)
#pragma unroll
            for (int ntl = 0; ntl < 2; ++ntl)
#pragma unroll
                for (int mt = 0; mt < 4; ++mt) {
                    accU[mt][ntl] = __builtin_amdgcn_mfma_f32_16x16x32_bf16(a[mt][s], bu[ntl][s], accU[mt][ntl], 0, 0, 0);
                    accV[mt][ntl] = __builtin_amdgcn_mfma_f32_16x16x32_bf16(a[mt][s], bv[ntl][s], accV[mt][ntl], 0, 0, 0);
                }

        // x double-buffer: store prefetched chunk, start next-next load
        if (kt < 15) {
            *(uint4*)&Xs[buf ^ 1][srow][sseg * 8] = xreg;
            if (kt < 14) xreg = *(const uint4*)(srcbase + (kt + 2) * 64);
        }
        __syncthreads();
#pragma unroll
        for (int ntl = 0; ntl < 2; ++ntl)
#pragma unroll
            for (int s = 0; s < 2; ++s) { bu[ntl][s] = nbu[ntl][s]; bv[ntl][s] = nbv[ntl][s]; }
    }

    // S = silu(U)*V*gate -> LDS (C-layout -> bf16 rows for A-layout reads)
#pragma unroll
    for (int mt = 0; mt < 4; ++mt)
#pragma unroll
        for (int ntl = 0; ntl < 2; ++ntl)
#pragma unroll
            for (int reg = 0; reg < 4; ++reg) {
                int row = mt * 16 + quad * 4 + reg;
                int col = w * 32 + ntl * 16 + m16;
                float u = accU[mt][ntl][reg], v = accV[mt][ntl][reg];
                float s = (u / (1.f + __expf(-u))) * v * gwL[row];
                Ss[row][col] = f2bf(s);
            }
    __syncthreads();

    const unsigned short* WoE = Wob + (size_t)e * DIM * RR;
#pragma unroll
    for (int c = 0; c < 2; ++c) {
        int n0 = (w + c * 8) * 64;
        f32x4 acc[4][4];
#pragma unroll
        for (int mt = 0; mt < 4; ++mt)
#pragma unroll
            for (int ntl = 0; ntl < 4; ++ntl) acc[mt][ntl] = zz;

        // prefetch first Wo frags
        bf16x8 b2[4], nb2[4];
#pragma unroll
        for (int ntl = 0; ntl < 4; ++ntl)
            b2[ntl] = *(const bf16x8*)(WoE + (size_t)(n0 + ntl * 16 + m16) * RR + quad * 8);

        for (int ks = 0; ks < RR; ks += 32) {
            bf16x8 a2[4];
#pragma unroll
            for (int mt = 0; mt < 4; ++mt)
                a2[mt] = *(const bf16x8*)&Ss[mt * 16 + m16][ks + quad * 8];
            if (ks < RR - 32) {
#pragma unroll
                for (int ntl = 0; ntl < 4; ++ntl)
                    nb2[ntl] = *(const bf16x8*)(WoE + (size_t)(n0 + ntl * 16 + m16) * RR + ks + 32 + quad * 8);
            }
#pragma unroll
            for (int ntl = 0; ntl < 4; ++ntl)
#pragma unroll
                for (int mt = 0; mt < 4; ++mt)
                    acc[mt][ntl] = __builtin_amdgcn_mfma_f32_16x16x32_bf16(a2[mt], b2[ntl], acc[mt][ntl], 0, 0, 0);
#pragma unroll
            for (int ntl = 0; ntl < 4; ++ntl) b2[ntl] = nb2[ntl];
        }

        if (ybuf) {
#pragma unroll
            for (int mt = 0; mt < 4; ++mt)
#pragma unroll
                for (int ntl = 0; ntl < 4; ++ntl)
#pragma unroll
                    for (int reg = 0; reg < 4; ++reg) {
                        int row = mt * 16 + quad * 4 + reg;
                        if (row < nt)
                            ybuf[(size_t)(start + row) * DIM + n0 + ntl * 16 + m16] =
                                acc[mt][ntl][reg];
                    }
        } else {
#pragma unroll
            for (int mt = 0; mt < 4; ++mt)
#pragma unroll
                for (int ntl = 0; ntl < 4; ++ntl)
#pragma unroll
                    for (int reg = 0; reg < 4; ++reg) {
                        int row = mt * 16 + quad * 4 + reg;
                        if (row < nt)
                            atomicAdd(&out[(size_t)tokL[row] * DIM + n0 + ntl * 16 + m16],
                                      acc[mt][ntl][reg]);
                    }
        }
    }
}

// ---------------- combine: out[t] = ybuf[slot0] + ybuf[slot1] ----------------
__global__ __launch_bounds__(256) void k_combine(const float* __restrict__ ybuf,
                                                 const int* __restrict__ slotOf,
                                                 float* __restrict__ out) {
    int t   = blockIdx.x;            // one token per block (256 thr x 4 floats)
    int seg = threadIdx.x;
    int s0 = slotOf[t * 2 + 0];
    int s1 = slotOf[t * 2 + 1];
    float4 a = *(const float4*)(ybuf + (size_t)s0 * DIM + seg * 4);
    float4 b = *(const float4*)(ybuf + (size_t)s1 * DIM + seg * 4);
    float4 r = { a.x + b.x, a.y + b.y, a.z + b.z, a.w + b.w };
    *(float4*)(out + (size_t)t * DIM + seg * 4) = r;
}

extern "C" void kernel_launch(void* const* d_in, const int* in_sizes, int n_in,
                              void* d_out, int out_size, void* d_ws, size_t ws_size,
                              hipStream_t stream) {
    const float* x  = (const float*)d_in[0];
    const float* gw = (const float*)d_in[1];
    const float* Wu = (const float*)d_in[2];
    const float* Wv = (const float*)d_in[3];
    const float* Wo = (const float*)d_in[4];
    float* out = (float*)d_out;

    int*   wsi     = (int*)d_ws;
    int*   counts  = wsi + 0;
    int*   offsets = wsi + 8;
    int*   fill    = wsi + 16;
    int*   topi    = wsi + 32;
    float* topw    = (float*)(wsi + 32 + 16384);
    int*   btok    = wsi + 32 + 32768;
    float* bw      = (float*)(wsi + 32 + 49152);
    int*   slotOf  = wsi + 32 + 65536;
    // routing region ends at byte 4*(32+81920) = 327,808
    float* gwT     = (float*)((char*)d_ws + 327808);          // 32 KB

    const size_t off_xb  = 393216;                              // 384 KB
    const size_t off_wub = off_xb  + (size_t)BN * DIM * 2;      // +16.78 MB
    const size_t off_wvb = off_wub + (size_t)NE * RR * DIM * 2; // +4 MB
    const size_t off_wob = off_wvb + (size_t)NE * RR * DIM * 2; // +4 MB
    const size_t off_yb  = off_wob + (size_t)NE * DIM * RR * 2; // +4 MB
    const size_t need    = off_yb  + (size_t)BN * 2 * DIM * 4;  // +67 MB ~= 92.4 MB

    unsigned short* xb  = (unsigned short*)((char*)d_ws + off_xb);
    unsigned short* Wub = (unsigned short*)((char*)d_ws + off_wub);
    unsigned short* Wvb = (unsigned short*)((char*)d_ws + off_wvb);
    unsigned short* Wob = (unsigned short*)((char*)d_ws + off_wob);
    bool use_ybuf = (ws_size >= need);
    float* ybuf = use_ybuf ? (float*)((char*)d_ws + off_yb) : nullptr;

    k_gwt<<<dim3(DIM * NE / 256), 256, 0, stream>>>(gw, gwT);
    k_router3<<<dim3(BN / 4), 256, 0, stream>>>(x, gwT, topi, topw, xb);
    k_count_scan<<<1, 256, 0, stream>>>(topi, counts, offsets, fill);
    k_fill2<<<dim3(BN * 2 / 256), 256, 0, stream>>>(topi, topw, offsets, fill,
                                                    btok, bw, slotOf);

    k_cvt_w<<<dim3(RR / 32, DIM / 32, NE), 256, 0, stream>>>(Wu, Wub, DIM, RR);
    k_cvt_w<<<dim3(RR / 32, DIM / 32, NE), 256, 0, stream>>>(Wv, Wvb, DIM, RR);
    k_cvt_w<<<dim3(DIM / 32, RR / 32, NE), 256, 0, stream>>>(Wo, Wob, RR, DIM);

    if (!use_ybuf)
        hipMemsetAsync(d_out, 0, (size_t)BN * DIM * sizeof(float), stream);

    k_expert_mfma<<<dim3(BN / 64 * NE), 512, 0, stream>>>(xb, Wub, Wvb, Wob,
                                                          counts, offsets, btok, bw,
                                                          ybuf, out);
    if (use_ybuf)
        k_combine<<<dim3(BN), 256, 0, stream>>>(ybuf, slotOf, out);
}

// Round 7
// 230.390 us; speedup vs baseline: 5.7678x; 1.1361x over previous
//
#include <hip/hip_runtime.h>
#include <math.h>

#define BN 8192      // B*N tokens
#define DIM 1024     // D
#define NE 8         // E experts
#define RR 256       // R

using bf16x8 = __attribute__((ext_vector_type(8))) short;
using f32x4  = __attribute__((ext_vector_type(4))) float;

__device__ inline unsigned short f2bf(float f) {
    unsigned int u = __float_as_uint(f);
    u = (u + 0x7fffu + ((u >> 16) & 1u)) >> 16;
    return (unsigned short)u;
}

// ---------------- gw transpose: [D][E] -> [E][D] fp32 ----------------
__global__ __launch_bounds__(256) void k_gwt(const float* __restrict__ gw,
                                             float* __restrict__ gwT) {
    int i = blockIdx.x * 256 + threadIdx.x;
    float v = gw[i];
    int d = i >> 3, e = i & 7;
    gwT[e * DIM + d] = v;
}

// ---------------- routing (coalesced, fp32, no atomics) + x->bf16 ----------
__global__ __launch_bounds__(256) void k_router3(const float* __restrict__ x,
                                                 const float* __restrict__ gwT,
                                                 int* __restrict__ topi,
                                                 float* __restrict__ topw,
                                                 unsigned short* __restrict__ xb) {
    int wid  = (blockIdx.x * blockDim.x + threadIdx.x) >> 6;
    int lane = threadIdx.x & 63;
    const float* xp = x + (size_t)wid * DIM + lane * 4;
    unsigned short* xbp = xb + (size_t)wid * DIM + lane * 4;
    float4 acc[NE];
#pragma unroll
    for (int e = 0; e < NE; ++e) acc[e] = float4{0.f, 0.f, 0.f, 0.f};
#pragma unroll
    for (int k = 0; k < 4; ++k) {
        float4 xv = *(const float4*)(xp + k * 256);
        ushort4 us = { f2bf(xv.x), f2bf(xv.y), f2bf(xv.z), f2bf(xv.w) };
        *(ushort4*)(xbp + k * 256) = us;
#pragma unroll
        for (int e = 0; e < NE; ++e) {
            float4 gv = *(const float4*)(gwT + e * DIM + k * 256 + lane * 4);
            acc[e].x += xv.x * gv.x; acc[e].y += xv.y * gv.y;
            acc[e].z += xv.z * gv.z; acc[e].w += xv.w * gv.w;
        }
    }
    float lg[NE];
#pragma unroll
    for (int e = 0; e < NE; ++e)
        lg[e] = (acc[e].x + acc[e].y) + (acc[e].z + acc[e].w);
#pragma unroll
    for (int off = 32; off; off >>= 1) {
#pragma unroll
        for (int e = 0; e < NE; ++e) lg[e] += __shfl_xor(lg[e], off, 64);
    }
    if (lane == 0) {
        float best = lg[0]; int bi = 0;
#pragma unroll
        for (int e = 1; e < NE; ++e) if (lg[e] > best) { best = lg[e]; bi = e; }
        float sec = -3.4e38f; int si = 0;
#pragma unroll
        for (int e = 0; e < NE; ++e) if (e != bi && lg[e] > sec) { sec = lg[e]; si = e; }
        float p  = __expf(sec - best);
        float w0 = 1.f / (1.f + p);
        float w1 = p * w0;
        topi[wid * 2 + 0] = bi;  topw[wid * 2 + 0] = w0;
        topi[wid * 2 + 1] = si;  topw[wid * 2 + 1] = w1;
    }
}

// -------- counts + offsets + tile-prefix, one block, no global atomics ------
__global__ __launch_bounds__(1024) void k_count_scan(const int* __restrict__ topi,
                                                     int* __restrict__ counts,
                                                     int* __restrict__ offsets,
                                                     int* __restrict__ fill,
                                                     int* __restrict__ tileOff) {
    __shared__ int sh[1024 * NE];
    int tid = threadIdx.x;
    int c[NE];
#pragma unroll
    for (int j = 0; j < NE; ++j) c[j] = 0;
    const int4* tp = (const int4*)topi;
    for (int i = tid; i < BN * 2 / 4; i += 1024) {
        int4 v = tp[i];
#pragma unroll
        for (int j = 0; j < NE; ++j)
            c[j] += (v.x == j) + (v.y == j) + (v.z == j) + (v.w == j);
    }
#pragma unroll
    for (int j = 0; j < NE; ++j) sh[tid * NE + j] = c[j];
    __syncthreads();
    for (int s = 512; s > 0; s >>= 1) {
        if (tid < s) {
#pragma unroll
            for (int j = 0; j < NE; ++j) sh[tid * NE + j] += sh[(tid + s) * NE + j];
        }
        __syncthreads();
    }
    if (tid == 0) {
        int acc = 0, tacc = 0;
        for (int j = 0; j < NE; ++j) {
            int cj = sh[j];
            counts[j]  = cj;
            offsets[j] = acc;   acc  += cj;
            tileOff[j] = tacc;  tacc += (cj + 63) >> 6;
        }
        tileOff[NE] = tacc;
    }
    if (tid < NE) fill[tid] = 0;
}

// ---------------- bucket fill: per-block aggregated atomics (8/block) -------
__global__ __launch_bounds__(256) void k_fill2(const int* __restrict__ topi,
                                               const float* __restrict__ topw,
                                               const int* __restrict__ offsets,
                                               int* __restrict__ fill,
                                               int* __restrict__ btok,
                                               float* __restrict__ bw) {
    int tid = threadIdx.x;
    int i = blockIdx.x * 256 + tid;
    int w = tid >> 6, lane = tid & 63;
    int e = topi[i];
    float wt = topw[i];

    __shared__ int waveCnt[4][NE];
    __shared__ int wavePre[4][NE];
    __shared__ int baseSh[NE];

    int myrank = 0;
    unsigned long long lt = (1ull << lane) - 1ull;
#pragma unroll
    for (int j = 0; j < NE; ++j) {
        unsigned long long m = __ballot(e == j);
        if (e == j) myrank = __popcll(m & lt);
        if (lane == 0) waveCnt[w][j] = __popcll(m);
    }
    __syncthreads();
    if (tid < NE) {
        int j = tid, acc = 0;
#pragma unroll
        for (int ww = 0; ww < 4; ++ww) { wavePre[ww][j] = acc; acc += waveCnt[ww][j]; }
        baseSh[j] = atomicAdd(&fill[j], acc);
    }
    __syncthreads();
    int slot = offsets[e] + baseSh[e] + wavePre[w][e] + myrank;
    btok[slot] = i >> 1;
    bw[slot]   = wt;
}

// -------- fused weight transpose+convert: 3 tensors, one launch -------------
// Wu,Wv: [E][1024][256] -> [E][256][1024];  Wo: [E][256][1024] -> [E][1024][256]
__global__ __launch_bounds__(256) void k_cvt3(const float* __restrict__ Wu,
                                              const float* __restrict__ Wv,
                                              const float* __restrict__ Wo,
                                              unsigned short* __restrict__ Wub,
                                              unsigned short* __restrict__ Wvb,
                                              unsigned short* __restrict__ Wob) {
    int z = blockIdx.y;
    int which = z >> 3, e = z & 7;
    int tile = blockIdx.x;                   // 256 tiles either way
    const float* in; unsigned short* out;
    int M, N, n0, m0;
    if (which < 2) {
        M = DIM; N = RR;
        n0 = (tile & 7) * 32;  m0 = (tile >> 3) * 32;
        in = which ? Wv : Wu;  out = which ? Wvb : Wub;
    } else {
        M = RR; N = DIM;
        n0 = (tile & 31) * 32; m0 = (tile >> 5) * 32;
        in = Wo; out = Wob;
    }
    __shared__ float t[32][33];
    int tx = threadIdx.x & 31, ty = threadIdx.x >> 5;
    const float* inE = in + (size_t)e * M * N;
    unsigned short* outE = out + (size_t)e * M * N;
#pragma unroll
    for (int i = ty; i < 32; i += 8)
        t[i][tx] = inE[(size_t)(m0 + i) * N + n0 + tx];
    __syncthreads();
#pragma unroll
    for (int i = ty; i < 32; i += 8)
        outE[(size_t)(n0 + i) * M + m0 + tx] = f2bf(t[tx][i]);
}

// ---------------- UV kernel: S = silu(X Wu)*(X Wv)*gate ---------------------
// grid: bid -> rt = bid&3 (64-r tile), mt_lin = bid>>2 (global 64-slot tile).
// block 256 thr = 4 waves; wave quadrant 32 tokens x 32 r (U and V).
__global__ __launch_bounds__(256, 2) void k_uv(
        const unsigned short* __restrict__ xb,
        const unsigned short* __restrict__ Wub,   // [E][R][D] k-contig
        const unsigned short* __restrict__ Wvb,
        const int* __restrict__ counts,
        const int* __restrict__ offsets,
        const int* __restrict__ tileOff,
        const int* __restrict__ btok,
        const float* __restrict__ bw,
        unsigned short* __restrict__ Sbuf) {
    int rt = blockIdx.x & 3;
    int mt_lin = blockIdx.x >> 2;
    if (mt_lin >= tileOff[NE]) return;
    int e = 0;
#pragma unroll
    for (int j = 1; j < NE; ++j) if (mt_lin >= tileOff[j]) e = j;
    int t0 = (mt_lin - tileOff[e]) * 64;
    int ne = counts[e];
    int nt = min(64, ne - t0);
    int start = offsets[e] + t0;

    int tid = threadIdx.x;
    int w = tid >> 6, lane = tid & 63;
    int m16 = lane & 15, quad = lane >> 4;
    int wm = w & 1, wn = w >> 1;

    __shared__ unsigned short As[64][72];    // 9.2 KB (pad: (row+quad)%8 spread)
    __shared__ unsigned short Bs[128][72];   // 18.4 KB (rows 0-63 Wu, 64-127 Wv)
    __shared__ int   tokL[64];
    __shared__ float gwL[64];

    if (tid < 64) {
        tokL[tid] = (tid < nt) ? btok[start + tid] : btok[start];
        gwL[tid]  = (tid < nt) ? bw[start + tid] : 0.f;
    }
    __syncthreads();

    const unsigned short* WuE = Wub + (size_t)e * RR * DIM + (size_t)rt * 64 * DIM;
    const unsigned short* WvE = Wvb + (size_t)e * RR * DIM + (size_t)rt * 64 * DIM;

    int arow = tid >> 2, apart = tid & 3;
    const unsigned short* asrc = xb + (size_t)tokL[arow] * DIM + apart * 16;
    int brow = tid >> 1, bhalf = tid & 1;
    const unsigned short* bsrc =
        (brow < 64 ? WuE + (size_t)brow * DIM : WvE + (size_t)(brow - 64) * DIM)
        + bhalf * 32;

    f32x4 accU[2][2], accV[2][2];
    f32x4 zz = {0.f, 0.f, 0.f, 0.f};
#pragma unroll
    for (int mt = 0; mt < 2; ++mt)
#pragma unroll
        for (int nl = 0; nl < 2; ++nl) { accU[mt][nl] = zz; accV[mt][nl] = zz; }

    for (int k0 = 0; k0 < DIM; k0 += 64) {
        __syncthreads();
        *(uint4*)&As[arow][apart * 16]     = *(const uint4*)(asrc + k0);
        *(uint4*)&As[arow][apart * 16 + 8] = *(const uint4*)(asrc + k0 + 8);
        *(uint4*)&Bs[brow][bhalf * 32]      = *(const uint4*)(bsrc + k0);
        *(uint4*)&Bs[brow][bhalf * 32 + 8]  = *(const uint4*)(bsrc + k0 + 8);
        *(uint4*)&Bs[brow][bhalf * 32 + 16] = *(const uint4*)(bsrc + k0 + 16);
        *(uint4*)&Bs[brow][bhalf * 32 + 24] = *(const uint4*)(bsrc + k0 + 24);
        __syncthreads();
#pragma unroll
        for (int ks = 0; ks < 2; ++ks) {
            bf16x8 a[2], bu[2], bv[2];
#pragma unroll
            for (int mt = 0; mt < 2; ++mt)
                a[mt] = *(const bf16x8*)&As[wm * 32 + mt * 16 + m16][ks * 32 + quad * 8];
#pragma unroll
            for (int nl = 0; nl < 2; ++nl) {
                bu[nl] = *(const bf16x8*)&Bs[wn * 32 + nl * 16 + m16][ks * 32 + quad * 8];
                bv[nl] = *(const bf16x8*)&Bs[64 + wn * 32 + nl * 16 + m16][ks * 32 + quad * 8];
            }
#pragma unroll
            for (int nl = 0; nl < 2; ++nl)
#pragma unroll
                for (int mt = 0; mt < 2; ++mt) {
                    accU[mt][nl] = __builtin_amdgcn_mfma_f32_16x16x32_bf16(a[mt], bu[nl], accU[mt][nl], 0, 0, 0);
                    accV[mt][nl] = __builtin_amdgcn_mfma_f32_16x16x32_bf16(a[mt], bv[nl], accV[mt][nl], 0, 0, 0);
                }
        }
    }

#pragma unroll
    for (int mt = 0; mt < 2; ++mt)
#pragma unroll
        for (int nl = 0; nl < 2; ++nl)
#pragma unroll
            for (int reg = 0; reg < 4; ++reg) {
                int trow = wm * 32 + mt * 16 + quad * 4 + reg;
                int rcol = rt * 64 + wn * 32 + nl * 16 + m16;
                float u = accU[mt][nl][reg], v = accV[mt][nl][reg];
                float s = (u / (1.f + __expf(-u))) * v * gwL[trow];
                if (trow < nt)
                    Sbuf[(size_t)(start + trow) * RR + rcol] = f2bf(s);
            }
}

// ---------------- down-proj: out[tok] += S * WoT ----------------------------
// grid: bid -> nd = bid&7 (128-d tile), mt_lin = bid>>3 (64-slot tile).
// block 256 thr = 4 waves; wave quadrant 32 slots x 64 d.
__global__ __launch_bounds__(256, 2) void k_down(
        const unsigned short* __restrict__ Sbuf,
        const unsigned short* __restrict__ Wob,   // [E][D][R] k-contig
        const int* __restrict__ counts,
        const int* __restrict__ offsets,
        const int* __restrict__ tileOff,
        const int* __restrict__ btok,
        float* __restrict__ out) {
    int nd = blockIdx.x & 7;
    int mt_lin = blockIdx.x >> 3;
    if (mt_lin >= tileOff[NE]) return;
    int e = 0;
#pragma unroll
    for (int j = 1; j < NE; ++j) if (mt_lin >= tileOff[j]) e = j;
    int t0 = (mt_lin - tileOff[e]) * 64;
    int ne = counts[e];
    int nt = min(64, ne - t0);
    int start = offsets[e] + t0;

    int tid = threadIdx.x;
    int w = tid >> 6, lane = tid & 63;
    int m16 = lane & 15, quad = lane >> 4;
    int wm = w & 1, wn = w >> 1;

    __shared__ unsigned short As[64][72];    // S tile 64 x 64r
    __shared__ unsigned short Bs[128][72];   // Wo rows (d) x 64r
    __shared__ int tokL[64];

    if (tid < 64)
        tokL[tid] = (tid < nt) ? btok[start + tid] : btok[start];
    __syncthreads();

    const unsigned short* WoE = Wob + (size_t)e * DIM * RR + (size_t)nd * 128 * RR;

    int arow = tid >> 2, apart = tid & 3;
    const unsigned short* asrc = Sbuf + (size_t)(start + arow) * RR + apart * 16;
    int brow = tid >> 1, bhalf = tid & 1;
    const unsigned short* bsrc = WoE + (size_t)brow * RR + bhalf * 32;

    f32x4 acc[2][4];
    f32x4 zz = {0.f, 0.f, 0.f, 0.f};
#pragma unroll
    for (int mt = 0; mt < 2; ++mt)
#pragma unroll
        for (int nl = 0; nl < 4; ++nl) acc[mt][nl] = zz;

    for (int k0 = 0; k0 < RR; k0 += 64) {
        __syncthreads();
        *(uint4*)&As[arow][apart * 16]     = *(const uint4*)(asrc + k0);
        *(uint4*)&As[arow][apart * 16 + 8] = *(const uint4*)(asrc + k0 + 8);
        *(uint4*)&Bs[brow][bhalf * 32]      = *(const uint4*)(bsrc + k0);
        *(uint4*)&Bs[brow][bhalf * 32 + 8]  = *(const uint4*)(bsrc + k0 + 8);
        *(uint4*)&Bs[brow][bhalf * 32 + 16] = *(const uint4*)(bsrc + k0 + 16);
        *(uint4*)&Bs[brow][bhalf * 32 + 24] = *(const uint4*)(bsrc + k0 + 24);
        __syncthreads();
#pragma unroll
        for (int ks = 0; ks < 2; ++ks) {
            bf16x8 a[2], b[4];
#pragma unroll
            for (int mt = 0; mt < 2; ++mt)
                a[mt] = *(const bf16x8*)&As[wm * 32 + mt * 16 + m16][ks * 32 + quad * 8];
#pragma unroll
            for (int nl = 0; nl < 4; ++nl)
                b[nl] = *(const bf16x8*)&Bs[wn * 64 + nl * 16 + m16][ks * 32 + quad * 8];
#pragma unroll
            for (int nl = 0; nl < 4; ++nl)
#pragma unroll
                for (int mt = 0; mt < 2; ++mt)
                    acc[mt][nl] = __builtin_amdgcn_mfma_f32_16x16x32_bf16(a[mt], b[nl], acc[mt][nl], 0, 0, 0);
        }
    }

#pragma unroll
    for (int mt = 0; mt < 2; ++mt)
#pragma unroll
        for (int nl = 0; nl < 4; ++nl)
#pragma unroll
            for (int reg = 0; reg < 4; ++reg) {
                int srow = wm * 32 + mt * 16 + quad * 4 + reg;
                int d    = nd * 128 + wn * 64 + nl * 16 + m16;
                if (srow < nt)
                    atomicAdd(&out[(size_t)tokL[srow] * DIM + d], acc[mt][nl][reg]);
            }
}

extern "C" void kernel_launch(void* const* d_in, const int* in_sizes, int n_in,
                              void* d_out, int out_size, void* d_ws, size_t ws_size,
                              hipStream_t stream) {
    const float* x  = (const float*)d_in[0];
    const float* gw = (const float*)d_in[1];
    const float* Wu = (const float*)d_in[2];
    const float* Wv = (const float*)d_in[3];
    const float* Wo = (const float*)d_in[4];
    float* out = (float*)d_out;

    int*   wsi     = (int*)d_ws;
    int*   counts  = wsi + 0;
    int*   offsets = wsi + 8;
    int*   fill    = wsi + 16;
    int*   tileOff = wsi + 24;              // 9 ints
    int*   topi    = wsi + 48;
    float* topw    = (float*)(wsi + 48 + 16384);
    int*   btok    = wsi + 48 + 32768;
    float* bw      = (float*)(wsi + 48 + 49152);
    // routing region ends at byte 4*(48+65536) = 262,336
    float* gwT     = (float*)((char*)d_ws + 327808 - 64 * 1024 + 65536);  // = 327,808? keep simple below
    gwT            = (float*)((char*)d_ws + 294912);                      // 288 KB, 32 KB long

    const size_t off_xb  = 393216;                                // 384 KB
    const size_t off_wub = off_xb  + (size_t)BN * DIM * 2;        // +16.78 MB
    const size_t off_wvb = off_wub + (size_t)NE * RR * DIM * 2;   // +4 MB
    const size_t off_wob = off_wvb + (size_t)NE * RR * DIM * 2;   // +4 MB
    const size_t off_sb  = off_wob + (size_t)NE * DIM * RR * 2;   // +4 MB
    // Sbuf: (16384 + 128) x 256 bf16 (+slack for padded tile reads)

    unsigned short* xb   = (unsigned short*)((char*)d_ws + off_xb);
    unsigned short* Wub  = (unsigned short*)((char*)d_ws + off_wub);
    unsigned short* Wvb  = (unsigned short*)((char*)d_ws + off_wvb);
    unsigned short* Wob  = (unsigned short*)((char*)d_ws + off_wob);
    unsigned short* Sbuf = (unsigned short*)((char*)d_ws + off_sb);

    hipMemsetAsync(d_out, 0, (size_t)BN * DIM * sizeof(float), stream);

    k_gwt<<<dim3(DIM * NE / 256), 256, 0, stream>>>(gw, gwT);
    k_router3<<<dim3(BN / 4), 256, 0, stream>>>(x, gwT, topi, topw, xb);
    k_count_scan<<<1, 1024, 0, stream>>>(topi, counts, offsets, fill, tileOff);
    k_fill2<<<dim3(BN * 2 / 256), 256, 0, stream>>>(topi, topw, offsets, fill, btok, bw);
    k_cvt3<<<dim3(256, 24), 256, 0, stream>>>(Wu, Wv, Wo, Wub, Wvb, Wob);

    // 264 = max Σ_e ceil(counts[e]/64); k_uv: x4 r-tiles, k_down: x8 d-tiles
    k_uv<<<dim3(264 * 4), 256, 0, stream>>>(xb, Wub, Wvb, counts, offsets, tileOff,
                                            btok, bw, Sbuf);
    k_down<<<dim3(264 * 8), 256, 0, stream>>>(Sbuf, Wob, counts, offsets, tileOff,
                                              btok, out);
}

// Round 8
// 204.674 us; speedup vs baseline: 6.4925x; 1.1256x over previous
//
#include <hip/hip_runtime.h>
#include <math.h>

#define BN 8192      // B*N tokens
#define DIM 1024     // D
#define NE 8         // E experts
#define RR 256       // R

using bf16x8 = __attribute__((ext_vector_type(8))) short;
using f32x4  = __attribute__((ext_vector_type(4))) float;

__device__ inline unsigned short f2bf(float f) {
    unsigned int u = __float_as_uint(f);
    u = (u + 0x7fffu + ((u >> 16) & 1u)) >> 16;
    return (unsigned short)u;
}

// ---------------- gw transpose: [D][E] -> [E][D] fp32 ----------------
__global__ __launch_bounds__(256) void k_gwt(const float* __restrict__ gw,
                                             float* __restrict__ gwT) {
    int i = blockIdx.x * 256 + threadIdx.x;
    float v = gw[i];
    int d = i >> 3, e = i & 7;
    gwT[e * DIM + d] = v;
}

// ---------------- routing (coalesced, fp32, no atomics) + x->bf16 ----------
__global__ __launch_bounds__(256) void k_router3(const float* __restrict__ x,
                                                 const float* __restrict__ gwT,
                                                 int* __restrict__ topi,
                                                 float* __restrict__ topw,
                                                 unsigned short* __restrict__ xb) {
    int wid  = (blockIdx.x * blockDim.x + threadIdx.x) >> 6;
    int lane = threadIdx.x & 63;
    const float* xp = x + (size_t)wid * DIM + lane * 4;
    unsigned short* xbp = xb + (size_t)wid * DIM + lane * 4;
    float4 acc[NE];
#pragma unroll
    for (int e = 0; e < NE; ++e) acc[e] = float4{0.f, 0.f, 0.f, 0.f};
#pragma unroll
    for (int k = 0; k < 4; ++k) {
        float4 xv = *(const float4*)(xp + k * 256);
        ushort4 us = { f2bf(xv.x), f2bf(xv.y), f2bf(xv.z), f2bf(xv.w) };
        *(ushort4*)(xbp + k * 256) = us;
#pragma unroll
        for (int e = 0; e < NE; ++e) {
            float4 gv = *(const float4*)(gwT + e * DIM + k * 256 + lane * 4);
            acc[e].x += xv.x * gv.x; acc[e].y += xv.y * gv.y;
            acc[e].z += xv.z * gv.z; acc[e].w += xv.w * gv.w;
        }
    }
    float lg[NE];
#pragma unroll
    for (int e = 0; e < NE; ++e)
        lg[e] = (acc[e].x + acc[e].y) + (acc[e].z + acc[e].w);
#pragma unroll
    for (int off = 32; off; off >>= 1) {
#pragma unroll
        for (int e = 0; e < NE; ++e) lg[e] += __shfl_xor(lg[e], off, 64);
    }
    if (lane == 0) {
        float best = lg[0]; int bi = 0;
#pragma unroll
        for (int e = 1; e < NE; ++e) if (lg[e] > best) { best = lg[e]; bi = e; }
        float sec = -3.4e38f; int si = 0;
#pragma unroll
        for (int e = 0; e < NE; ++e) if (e != bi && lg[e] > sec) { sec = lg[e]; si = e; }
        float p  = __expf(sec - best);
        float w0 = 1.f / (1.f + p);
        float w1 = p * w0;
        topi[wid * 2 + 0] = bi;  topw[wid * 2 + 0] = w0;
        topi[wid * 2 + 1] = si;  topw[wid * 2 + 1] = w1;
    }
}

// -------- counts + offsets + tile-prefix, one block, no global atomics ------
__global__ __launch_bounds__(1024) void k_count_scan(const int* __restrict__ topi,
                                                     int* __restrict__ counts,
                                                     int* __restrict__ offsets,
                                                     int* __restrict__ fill,
                                                     int* __restrict__ tileOff) {
    __shared__ int sh[1024 * NE];
    int tid = threadIdx.x;
    int c[NE];
#pragma unroll
    for (int j = 0; j < NE; ++j) c[j] = 0;
    const int4* tp = (const int4*)topi;
    for (int i = tid; i < BN * 2 / 4; i += 1024) {
        int4 v = tp[i];
#pragma unroll
        for (int j = 0; j < NE; ++j)
            c[j] += (v.x == j) + (v.y == j) + (v.z == j) + (v.w == j);
    }
#pragma unroll
    for (int j = 0; j < NE; ++j) sh[tid * NE + j] = c[j];
    __syncthreads();
    for (int s = 512; s > 0; s >>= 1) {
        if (tid < s) {
#pragma unroll
            for (int j = 0; j < NE; ++j) sh[tid * NE + j] += sh[(tid + s) * NE + j];
        }
        __syncthreads();
    }
    if (tid == 0) {
        int acc = 0, tacc = 0;
        for (int j = 0; j < NE; ++j) {
            int cj = sh[j];
            counts[j]  = cj;
            offsets[j] = acc;   acc  += cj;
            tileOff[j] = tacc;  tacc += (cj + 63) >> 6;
        }
        tileOff[NE] = tacc;
    }
    if (tid < NE) fill[tid] = 0;
}

// ---------------- bucket fill: per-block aggregated atomics (8/block) -------
__global__ __launch_bounds__(256) void k_fill2(const int* __restrict__ topi,
                                               const float* __restrict__ topw,
                                               const int* __restrict__ offsets,
                                               int* __restrict__ fill,
                                               int* __restrict__ btok,
                                               float* __restrict__ bw,
                                               int* __restrict__ slotOf) {
    int tid = threadIdx.x;
    int i = blockIdx.x * 256 + tid;
    int w = tid >> 6, lane = tid & 63;
    int e = topi[i];
    float wt = topw[i];

    __shared__ int waveCnt[4][NE];
    __shared__ int wavePre[4][NE];
    __shared__ int baseSh[NE];

    int myrank = 0;
    unsigned long long lt = (1ull << lane) - 1ull;
#pragma unroll
    for (int j = 0; j < NE; ++j) {
        unsigned long long m = __ballot(e == j);
        if (e == j) myrank = __popcll(m & lt);
        if (lane == 0) waveCnt[w][j] = __popcll(m);
    }
    __syncthreads();
    if (tid < NE) {
        int j = tid, acc = 0;
#pragma unroll
        for (int ww = 0; ww < 4; ++ww) { wavePre[ww][j] = acc; acc += waveCnt[ww][j]; }
        baseSh[j] = atomicAdd(&fill[j], acc);
    }
    __syncthreads();
    int slot = offsets[e] + baseSh[e] + wavePre[w][e] + myrank;
    btok[slot] = i >> 1;
    bw[slot]   = wt;
    slotOf[i]  = slot;
}

// -------- fused weight transpose+convert: 3 tensors, one launch -------------
__global__ __launch_bounds__(256) void k_cvt3(const float* __restrict__ Wu,
                                              const float* __restrict__ Wv,
                                              const float* __restrict__ Wo,
                                              unsigned short* __restrict__ Wub,
                                              unsigned short* __restrict__ Wvb,
                                              unsigned short* __restrict__ Wob) {
    int z = blockIdx.y;
    int which = z >> 3, e = z & 7;
    int tile = blockIdx.x;
    const float* in; unsigned short* out;
    int M, N, n0, m0;
    if (which < 2) {
        M = DIM; N = RR;
        n0 = (tile & 7) * 32;  m0 = (tile >> 3) * 32;
        in = which ? Wv : Wu;  out = which ? Wvb : Wub;
    } else {
        M = RR; N = DIM;
        n0 = (tile & 31) * 32; m0 = (tile >> 5) * 32;
        in = Wo; out = Wob;
    }
    __shared__ float t[32][33];
    int tx = threadIdx.x & 31, ty = threadIdx.x >> 5;
    const float* inE = in + (size_t)e * M * N;
    unsigned short* outE = out + (size_t)e * M * N;
#pragma unroll
    for (int i = ty; i < 32; i += 8)
        t[i][tx] = inE[(size_t)(m0 + i) * N + n0 + tx];
    __syncthreads();
#pragma unroll
    for (int i = ty; i < 32; i += 8)
        outE[(size_t)(n0 + i) * M + m0 + tx] = f2bf(t[tx][i]);
}

// ---------------- UV kernel: S = silu(X Wu)*(X Wv)*gate ---------------------
// grid: bid -> rt = bid&3 (64-r tile), mt_lin = bid>>2 (64-slot tile).
// Register-prefetch double buffer: chunk k+1 loads overlap chunk-k MFMA.
__global__ __launch_bounds__(256, 2) void k_uv(
        const unsigned short* __restrict__ xb,
        const unsigned short* __restrict__ Wub,   // [E][R][D] k-contig
        const unsigned short* __restrict__ Wvb,
        const int* __restrict__ counts,
        const int* __restrict__ offsets,
        const int* __restrict__ tileOff,
        const int* __restrict__ btok,
        const float* __restrict__ bw,
        unsigned short* __restrict__ Sbuf) {
    int rt = blockIdx.x & 3;
    int mt_lin = blockIdx.x >> 2;
    if (mt_lin >= tileOff[NE]) return;
    int e = 0;
#pragma unroll
    for (int j = 1; j < NE; ++j) if (mt_lin >= tileOff[j]) e = j;
    int t0 = (mt_lin - tileOff[e]) * 64;
    int ne = counts[e];
    int nt = min(64, ne - t0);
    int start = offsets[e] + t0;

    int tid = threadIdx.x;
    int w = tid >> 6, lane = tid & 63;
    int m16 = lane & 15, quad = lane >> 4;
    int wm = w & 1, wn = w >> 1;

    __shared__ unsigned short As[64][72];
    __shared__ unsigned short Bs[128][72];
    __shared__ int   tokL[64];
    __shared__ float gwL[64];

    if (tid < 64) {
        tokL[tid] = (tid < nt) ? btok[start + tid] : btok[start];
        gwL[tid]  = (tid < nt) ? bw[start + tid] : 0.f;
    }
    __syncthreads();

    const unsigned short* WuE = Wub + (size_t)e * RR * DIM + (size_t)rt * 64 * DIM;
    const unsigned short* WvE = Wvb + (size_t)e * RR * DIM + (size_t)rt * 64 * DIM;

    int arow = tid >> 2, apart = tid & 3;
    const unsigned short* asrc = xb + (size_t)tokL[arow] * DIM + apart * 16;
    int brow = tid >> 1, bhalf = tid & 1;
    const unsigned short* bsrc =
        (brow < 64 ? WuE + (size_t)brow * DIM : WvE + (size_t)(brow - 64) * DIM)
        + bhalf * 32;

    f32x4 accU[2][2], accV[2][2];
    f32x4 zz = {0.f, 0.f, 0.f, 0.f};
#pragma unroll
    for (int mt = 0; mt < 2; ++mt)
#pragma unroll
        for (int nl = 0; nl < 2; ++nl) { accU[mt][nl] = zz; accV[mt][nl] = zz; }

    uint4 pa0 = *(const uint4*)(asrc);
    uint4 pa1 = *(const uint4*)(asrc + 8);
    uint4 pb0 = *(const uint4*)(bsrc);
    uint4 pb1 = *(const uint4*)(bsrc + 8);
    uint4 pb2 = *(const uint4*)(bsrc + 16);
    uint4 pb3 = *(const uint4*)(bsrc + 24);

    for (int kt = 0; kt < 16; ++kt) {
        __syncthreads();   // prior chunk's readers done
        *(uint4*)&As[arow][apart * 16]      = pa0;
        *(uint4*)&As[arow][apart * 16 + 8]  = pa1;
        *(uint4*)&Bs[brow][bhalf * 32]      = pb0;
        *(uint4*)&Bs[brow][bhalf * 32 + 8]  = pb1;
        *(uint4*)&Bs[brow][bhalf * 32 + 16] = pb2;
        *(uint4*)&Bs[brow][bhalf * 32 + 24] = pb3;
        __syncthreads();
        if (kt < 15) {      // issue next-chunk loads; latency overlaps MFMA below
            int k1 = (kt + 1) * 64;
            pa0 = *(const uint4*)(asrc + k1);
            pa1 = *(const uint4*)(asrc + k1 + 8);
            pb0 = *(const uint4*)(bsrc + k1);
            pb1 = *(const uint4*)(bsrc + k1 + 8);
            pb2 = *(const uint4*)(bsrc + k1 + 16);
            pb3 = *(const uint4*)(bsrc + k1 + 24);
        }
#pragma unroll
        for (int ks = 0; ks < 2; ++ks) {
            bf16x8 a[2], bu[2], bv[2];
#pragma unroll
            for (int mt = 0; mt < 2; ++mt)
                a[mt] = *(const bf16x8*)&As[wm * 32 + mt * 16 + m16][ks * 32 + quad * 8];
#pragma unroll
            for (int nl = 0; nl < 2; ++nl) {
                bu[nl] = *(const bf16x8*)&Bs[wn * 32 + nl * 16 + m16][ks * 32 + quad * 8];
                bv[nl] = *(const bf16x8*)&Bs[64 + wn * 32 + nl * 16 + m16][ks * 32 + quad * 8];
            }
#pragma unroll
            for (int nl = 0; nl < 2; ++nl)
#pragma unroll
                for (int mt = 0; mt < 2; ++mt) {
                    accU[mt][nl] = __builtin_amdgcn_mfma_f32_16x16x32_bf16(a[mt], bu[nl], accU[mt][nl], 0, 0, 0);
                    accV[mt][nl] = __builtin_amdgcn_mfma_f32_16x16x32_bf16(a[mt], bv[nl], accV[mt][nl], 0, 0, 0);
                }
        }
    }

#pragma unroll
    for (int mt = 0; mt < 2; ++mt)
#pragma unroll
        for (int nl = 0; nl < 2; ++nl)
#pragma unroll
            for (int reg = 0; reg < 4; ++reg) {
                int trow = wm * 32 + mt * 16 + quad * 4 + reg;
                int rcol = rt * 64 + wn * 32 + nl * 16 + m16;
                float u = accU[mt][nl][reg], v = accV[mt][nl][reg];
                float s = (u / (1.f + __expf(-u))) * v * gwL[trow];
                if (trow < nt)
                    Sbuf[(size_t)(start + trow) * RR + rcol] = f2bf(s);
            }
}

// ---------------- down-proj: ybuf[slot] = S * WoT (no atomics) --------------
// grid: bid -> nd = bid&7 (128-d tile), mt_lin = bid>>3 (64-slot tile).
__global__ __launch_bounds__(256, 2) void k_down(
        const unsigned short* __restrict__ Sbuf,
        const unsigned short* __restrict__ Wob,   // [E][D][R] k-contig
        const int* __restrict__ counts,
        const int* __restrict__ offsets,
        const int* __restrict__ tileOff,
        const int* __restrict__ btok,
        float* __restrict__ ybuf,                 // [slots][D] fp32, or null
        float* __restrict__ out) {
    int nd = blockIdx.x & 7;
    int mt_lin = blockIdx.x >> 3;
    if (mt_lin >= tileOff[NE]) return;
    int e = 0;
#pragma unroll
    for (int j = 1; j < NE; ++j) if (mt_lin >= tileOff[j]) e = j;
    int t0 = (mt_lin - tileOff[e]) * 64;
    int ne = counts[e];
    int nt = min(64, ne - t0);
    int start = offsets[e] + t0;

    int tid = threadIdx.x;
    int w = tid >> 6, lane = tid & 63;
    int m16 = lane & 15, quad = lane >> 4;
    int wm = w & 1, wn = w >> 1;

    __shared__ unsigned short As[64][72];
    __shared__ unsigned short Bs[128][72];
    __shared__ int tokL[64];

    if (tid < 64)
        tokL[tid] = (tid < nt) ? btok[start + tid] : btok[start];
    __syncthreads();

    const unsigned short* WoE = Wob + (size_t)e * DIM * RR + (size_t)nd * 128 * RR;

    int arow = tid >> 2, apart = tid & 3;
    const unsigned short* asrc = Sbuf + (size_t)(start + arow) * RR + apart * 16;
    int brow = tid >> 1, bhalf = tid & 1;
    const unsigned short* bsrc = WoE + (size_t)brow * RR + bhalf * 32;

    f32x4 acc[2][4];
    f32x4 zz = {0.f, 0.f, 0.f, 0.f};
#pragma unroll
    for (int mt = 0; mt < 2; ++mt)
#pragma unroll
        for (int nl = 0; nl < 4; ++nl) acc[mt][nl] = zz;

    uint4 pa0 = *(const uint4*)(asrc);
    uint4 pa1 = *(const uint4*)(asrc + 8);
    uint4 pb0 = *(const uint4*)(bsrc);
    uint4 pb1 = *(const uint4*)(bsrc + 8);
    uint4 pb2 = *(const uint4*)(bsrc + 16);
    uint4 pb3 = *(const uint4*)(bsrc + 24);

    for (int kt = 0; kt < 4; ++kt) {
        __syncthreads();
        *(uint4*)&As[arow][apart * 16]      = pa0;
        *(uint4*)&As[arow][apart * 16 + 8]  = pa1;
        *(uint4*)&Bs[brow][bhalf * 32]      = pb0;
        *(uint4*)&Bs[brow][bhalf * 32 + 8]  = pb1;
        *(uint4*)&Bs[brow][bhalf * 32 + 16] = pb2;
        *(uint4*)&Bs[brow][bhalf * 32 + 24] = pb3;
        __syncthreads();
        if (kt < 3) {
            int k1 = (kt + 1) * 64;
            pa0 = *(const uint4*)(asrc + k1);
            pa1 = *(const uint4*)(asrc + k1 + 8);
            pb0 = *(const uint4*)(bsrc + k1);
            pb1 = *(const uint4*)(bsrc + k1 + 8);
            pb2 = *(const uint4*)(bsrc + k1 + 16);
            pb3 = *(const uint4*)(bsrc + k1 + 24);
        }
#pragma unroll
        for (int ks = 0; ks < 2; ++ks) {
            bf16x8 a[2], b[4];
#pragma unroll
            for (int mt = 0; mt < 2; ++mt)
                a[mt] = *(const bf16x8*)&As[wm * 32 + mt * 16 + m16][ks * 32 + quad * 8];
#pragma unroll
            for (int nl = 0; nl < 4; ++nl)
                b[nl] = *(const bf16x8*)&Bs[wn * 64 + nl * 16 + m16][ks * 32 + quad * 8];
#pragma unroll
            for (int nl = 0; nl < 4; ++nl)
#pragma unroll
                for (int mt = 0; mt < 2; ++mt)
                    acc[mt][nl] = __builtin_amdgcn_mfma_f32_16x16x32_bf16(a[mt], b[nl], acc[mt][nl], 0, 0, 0);
        }
    }

    if (ybuf) {
#pragma unroll
        for (int mt = 0; mt < 2; ++mt)
#pragma unroll
            for (int nl = 0; nl < 4; ++nl)
#pragma unroll
                for (int reg = 0; reg < 4; ++reg) {
                    int srow = wm * 32 + mt * 16 + quad * 4 + reg;
                    int d    = nd * 128 + wn * 64 + nl * 16 + m16;
                    if (srow < nt)
                        ybuf[(size_t)(start + srow) * DIM + d] = acc[mt][nl][reg];
                }
    } else {
#pragma unroll
        for (int mt = 0; mt < 2; ++mt)
#pragma unroll
            for (int nl = 0; nl < 4; ++nl)
#pragma unroll
                for (int reg = 0; reg < 4; ++reg) {
                    int srow = wm * 32 + mt * 16 + quad * 4 + reg;
                    int d    = nd * 128 + wn * 64 + nl * 16 + m16;
                    if (srow < nt)
                        atomicAdd(&out[(size_t)tokL[srow] * DIM + d], acc[mt][nl][reg]);
                }
    }
}

// ---------------- combine: out[t] = ybuf[slot0] + ybuf[slot1] ----------------
__global__ __launch_bounds__(256) void k_combine(const float* __restrict__ ybuf,
                                                 const int* __restrict__ slotOf,
                                                 float* __restrict__ out) {
    int t   = blockIdx.x;
    int seg = threadIdx.x;
    int s0 = slotOf[t * 2 + 0];
    int s1 = slotOf[t * 2 + 1];
    float4 a = *(const float4*)(ybuf + (size_t)s0 * DIM + seg * 4);
    float4 b = *(const float4*)(ybuf + (size_t)s1 * DIM + seg * 4);
    float4 r = { a.x + b.x, a.y + b.y, a.z + b.z, a.w + b.w };
    *(float4*)(out + (size_t)t * DIM + seg * 4) = r;
}

extern "C" void kernel_launch(void* const* d_in, const int* in_sizes, int n_in,
                              void* d_out, int out_size, void* d_ws, size_t ws_size,
                              hipStream_t stream) {
    const float* x  = (const float*)d_in[0];
    const float* gw = (const float*)d_in[1];
    const float* Wu = (const float*)d_in[2];
    const float* Wv = (const float*)d_in[3];
    const float* Wo = (const float*)d_in[4];
    float* out = (float*)d_out;

    int*   wsi     = (int*)d_ws;
    int*   counts  = wsi + 0;
    int*   offsets = wsi + 8;
    int*   fill    = wsi + 16;
    int*   tileOff = wsi + 24;              // 9 ints
    int*   topi    = wsi + 48;
    float* topw    = (float*)(wsi + 48 + 16384);
    int*   btok    = wsi + 48 + 32768;
    float* bw      = (float*)(wsi + 48 + 49152);
    int*   slotOf  = wsi + 48 + 65536;
    // routing region ends at byte 4*(48+81920) = 327,872
    float* gwT     = (float*)((char*)d_ws + 327872);              // 32 KB

    const size_t off_xb  = 393216;                                // 384 KB
    const size_t off_wub = off_xb  + (size_t)BN * DIM * 2;        // +16.78 MB
    const size_t off_wvb = off_wub + (size_t)NE * RR * DIM * 2;   // +4 MB
    const size_t off_wob = off_wvb + (size_t)NE * RR * DIM * 2;   // +4 MB
    const size_t off_sb  = off_wob + (size_t)NE * DIM * RR * 2;   // +4 MB
    const size_t off_yb  = off_sb  + (size_t)(BN * 2 + 128) * RR * 2; // +8.45 MB
    const size_t need_yb = off_yb  + (size_t)BN * 2 * DIM * 4;    // +67 MB ≈ 105 MB

    unsigned short* xb   = (unsigned short*)((char*)d_ws + off_xb);
    unsigned short* Wub  = (unsigned short*)((char*)d_ws + off_wub);
    unsigned short* Wvb  = (unsigned short*)((char*)d_ws + off_wvb);
    unsigned short* Wob  = (unsigned short*)((char*)d_ws + off_wob);
    unsigned short* Sbuf = (unsigned short*)((char*)d_ws + off_sb);
    bool use_ybuf = (ws_size >= need_yb);
    float* ybuf = use_ybuf ? (float*)((char*)d_ws + off_yb) : nullptr;

    k_gwt<<<dim3(DIM * NE / 256), 256, 0, stream>>>(gw, gwT);
    k_router3<<<dim3(BN / 4), 256, 0, stream>>>(x, gwT, topi, topw, xb);
    k_count_scan<<<1, 1024, 0, stream>>>(topi, counts, offsets, fill, tileOff);
    k_fill2<<<dim3(BN * 2 / 256), 256, 0, stream>>>(topi, topw, offsets, fill,
                                                    btok, bw, slotOf);
    k_cvt3<<<dim3(256, 24), 256, 0, stream>>>(Wu, Wv, Wo, Wub, Wvb, Wob);

    if (!use_ybuf)
        hipMemsetAsync(d_out, 0, (size_t)BN * DIM * sizeof(float), stream);

    k_uv<<<dim3(264 * 4), 256, 0, stream>>>(xb, Wub, Wvb, counts, offsets, tileOff,
                                            btok, bw, Sbuf);
    k_down<<<dim3(264 * 8), 256, 0, stream>>>(Sbuf, Wob, counts, offsets, tileOff,
                                              btok, ybuf, out);
    if (use_ybuf)
        k_combine<<<dim3(BN), 256, 0, stream>>>(ybuf, slotOf, out);
}